// Round 5
// baseline (772.269 us; speedup 1.0000x reference)
//
#include <hip/hip_runtime.h>

#define BB 32
#define NN 576
#define DD 1024
#define KK 128
#define HS_N 577

// ---------------- norm kernel: inv[b,n] = 1/||feats[b,n,:]|| ----------------
__global__ __launch_bounds__(256) void norm_kernel(const float* __restrict__ hs,
                                                   float* __restrict__ inv) {
    int row = blockIdx.x;              // b*NN + n
    int b = row / NN, n = row % NN;
    const float4* p = (const float4*)(hs + ((size_t)b * HS_N + n + 1) * DD);
    int t = threadIdx.x;
    float4 v = p[t];
    double s = (double)v.x * v.x + (double)v.y * v.y + (double)v.z * v.z + (double)v.w * v.w;
    for (int off = 32; off; off >>= 1) s += __shfl_xor(s, off);
    __shared__ double wsum[4];
    int lane = t & 63, w = t >> 6;
    if (lane == 0) wsum[w] = s;
    __syncthreads();
    if (t == 0) {
        double tot = wsum[0] + wsum[1] + wsum[2] + wsum[3];
        inv[row] = 1.0f / (float)sqrt(tot);
    }
}

// ---------------- sim GEMM (symmetric): only 45 upper-tri 64x64 tile pairs --
#define KC 16
#define LDT 68   // padded LDS stride
#define TLD 68   // transpose-bounce stride
__global__ __launch_bounds__(256) void sim_kernel(const float* __restrict__ hs,
                                                  const float* __restrict__ inv,
                                                  float* __restrict__ sim) {
    int b = blockIdx.z;
    int l = blockIdx.x;                // 0..44 -> (ti,tj), ti<=tj
    int ti = 0;
    while (l >= 9 - ti) { l -= 9 - ti; ti++; }
    int tj = ti + l;
    int m0 = ti * 64, n0 = tj * 64;
    const float* feats = hs + ((size_t)b * HS_N + 1) * DD;
    __shared__ float As[KC * LDT];
    __shared__ float Bs[KC * LDT];
    __shared__ float tile[64 * TLD];
    int t = threadIdx.x;
    int lrow = t >> 2, lc4 = (t & 3) << 2;     // 64 rows x 4 float4-cols
    float invA = inv[b * NN + m0 + lrow];
    float invB = inv[b * NN + n0 + lrow];
    const float* gA = feats + (size_t)(m0 + lrow) * DD + lc4;
    const float* gB = feats + (size_t)(n0 + lrow) * DD + lc4;
    int tx = t & 15, ty = t >> 4;
    float acc[4][4] = {};
    for (int k0 = 0; k0 < DD; k0 += KC) {
        float4 a = *(const float4*)(gA + k0);
        float4 bv = *(const float4*)(gB + k0);
        __syncthreads();
        // store transposed [k][m], scaled at load (matches reference normalize-then-dot)
        As[(lc4 + 0) * LDT + lrow] = a.x * invA;
        As[(lc4 + 1) * LDT + lrow] = a.y * invA;
        As[(lc4 + 2) * LDT + lrow] = a.z * invA;
        As[(lc4 + 3) * LDT + lrow] = a.w * invA;
        Bs[(lc4 + 0) * LDT + lrow] = bv.x * invB;
        Bs[(lc4 + 1) * LDT + lrow] = bv.y * invB;
        Bs[(lc4 + 2) * LDT + lrow] = bv.z * invB;
        Bs[(lc4 + 3) * LDT + lrow] = bv.w * invB;
        __syncthreads();
#pragma unroll
        for (int kk = 0; kk < KC; kk++) {
            float4 av = *(const float4*)&As[kk * LDT + (tx << 2)];
            float4 bw = *(const float4*)&Bs[kk * LDT + (ty << 2)];
            float aa[4] = {av.x, av.y, av.z, av.w};
            float bb[4] = {bw.x, bw.y, bw.z, bw.w};
#pragma unroll
            for (int i = 0; i < 4; i++)
#pragma unroll
                for (int j = 0; j < 4; j++) acc[i][j] += aa[i] * bb[j];
        }
    }
    // normal-orientation tile write (coalesced float4)
#pragma unroll
    for (int i = 0; i < 4; i++) {
        size_t m = m0 + (tx << 2) + i;
        float4 o = {acc[i][0], acc[i][1], acc[i][2], acc[i][3]};
        *(float4*)(sim + ((size_t)b * NN + m) * NN + n0 + (ty << 2)) = o;
    }
    if (ti != tj) {
        // mirror tile via LDS bounce; same float values -> bitwise symmetric
        __syncthreads();
#pragma unroll
        for (int i = 0; i < 4; i++) {
            float4 o = {acc[i][0], acc[i][1], acc[i][2], acc[i][3]};
            *(float4*)&tile[((tx << 2) + i) * TLD + (ty << 2)] = o;
        }
        __syncthreads();
#pragma unroll
        for (int r = 0; r < 4; r++) {
            int a = (tx << 2) + r;                 // local n index (output row)
            float4 o;
            o.x = tile[((ty << 2) + 0) * TLD + a];
            o.y = tile[((ty << 2) + 1) * TLD + a];
            o.z = tile[((ty << 2) + 2) * TLD + a];
            o.w = tile[((ty << 2) + 3) * TLD + a];
            *(float4*)(sim + ((size_t)b * NN + n0 + a) * NN + m0 + (ty << 2)) = o;
        }
    }
}

// -------- init gains on all CUs: g0[b,m] = sum_n max(sim[b,m,n],0) ----------
// Also zeroes the 576-float pad row after sim (dummy-column reads for b=31
// land there; b<31 dummy reads hit batch b+1's sim -- finite either way, and
// d == 0 exactly for the dummy column since its ovnw has o == nw == 0).
__global__ __launch_bounds__(256) void init_gain_kernel(const float* __restrict__ sim,
                                                        double* __restrict__ g0,
                                                        float* __restrict__ pad) {
    if (blockIdx.x == 0 && blockIdx.y == 0) {
        int tt = threadIdx.x;
        pad[tt] = 0.f; pad[tt + 256] = 0.f;
        if (tt < 64) pad[tt + 512] = 0.f;
    }
    int b = blockIdx.y;
    int m = (blockIdx.x << 2) + (threadIdx.x >> 6);
    int lane = threadIdx.x & 63;
    const float* row = sim + ((size_t)b * NN + m) * NN;
    double s = 0.0;
#pragma unroll
    for (int j = 0; j < 9; j++) s += (double)fmaxf(row[(j << 6) + lane], 0.f);
    for (int off = 32; off; off >>= 1) s += __shfl_xor(s, off);
    if (lane == 0) g0[b * NN + m] = s;
}

// ------- selection: 9 waves x 1 candidate + pipelined ILP-8 ----------------
// v5: round-4 proved the explicit double-buffer pipeline (+153 us) but one
// wave/SIMD still stalls ~63% of cycles (VALUBusy 28% per active CU) -- a
// single wave cannot hide L2 latency + f64-add chains. Round 1 proved 9
// waves alone (no pipeline, with vote overhead) roughly ties 1-wave. This
// version combines the validated pieces: 576 threads (9 waves -> 2-3/SIMD
// TLP), ILP-8 double-buffered pipeline (per-thread regs ~100 < the 170/wave
// cap that 3 waves/SIMD requires; 3x8 loads in flight per SIMD), med3 math,
// no vote. Gains accumulate in the SAME chlist order (j,q ascending) ->
// bitwise-identical trajectory. Argmax/epilogue = round-1-validated 9-wave
// code (absmax 0.0). Dummy-column padding now to x8 (col NN, ovnw[NN]=(0,0)
// -> d == 0 exactly); clamped tail prefetch feeds no compute.
#define LOAD_BUF8(NQ, X, ON, J)                                                \
    {                                                                          \
        int jj8 = (J) << 3;                                                    \
        _Pragma("unroll") for (int q = 0; q < 8; q++)                          \
            NQ[q] = chlist[jj8 + q]; /* wave-uniform */                        \
        _Pragma("unroll") for (int q = 0; q < 8; q++)                          \
            X[q] = S[(size_t)NQ[q] * NN + t];                                  \
        _Pragma("unroll") for (int q = 0; q < 8; q++) ON[q] = ovnw[NQ[q]];     \
    }

#define COMP_BUF8(X, ON)                                                       \
    {                                                                          \
        _Pragma("unroll") for (int q = 0; q < 8; q++) {                        \
            float o = ON[q].x, nw = ON[q].y;                                   \
            gg += (double)(o - fminf(fmaxf(X[q], o), nw));                     \
        }                                                                      \
    }

__global__ __launch_bounds__(576, 1) void select_kernel(const float* __restrict__ sim,
                                                        const double* __restrict__ g0,
                                                        const float* __restrict__ cls,
                                                        float* __restrict__ out_idx,
                                                        int* __restrict__ gsorted) {
    int b = blockIdx.x;
    const float* S = sim + (size_t)b * NN * NN;
    int t = threadIdx.x, lane = t & 63, w = t >> 6;   // w in 0..8
    __shared__ float2 ovnw[NN + 1];        // (old cmax, new cmax); slot NN = dummy
    __shared__ int    chlist[NN + 8];
    __shared__ unsigned long long chmask[9];
    __shared__ double rv[9];
    __shared__ int    ri[9];
    __shared__ float  selseq[KK];
    __shared__ int    wcnt[9];

    double gg = g0[b * NN + t];
    double cl = (double)cls[b * NN + t];
    float mycmax = 0.f;
    bool sel = false;
    const int c0 = t;
    if (t == 0) ovnw[NN] = make_float2(0.f, 0.f);

    for (int k = 0; k < KK; k++) {
        // ---- phase 1: delta-update over step-(k-1) changed columns ----
        if (k > 0) {
            int pos = 0;
#pragma unroll
            for (int q = 0; q < 9; q++) {
                unsigned long long m = chmask[q];
                if ((m >> lane) & 1ull)
                    chlist[pos + __popcll(m & ((1ull << lane) - 1ull))] = (q << 6) + lane;
                pos += __popcll(m);
            }
            int cc = pos;
            int padc = (8 - (cc & 7)) & 7;
            if (lane < padc) chlist[cc + lane] = NN;   // dummy col: d == 0 exactly
            int nbat = (cc + padc) >> 3;               // >= 1 (winner's row always changes)

            int nqA[8]; float xA[8]; float2 onA[8];
            int nqB[8]; float xB[8]; float2 onB[8];
            LOAD_BUF8(nqA, xA, onA, 0);
            for (int j = 0; j < nbat; ) {
                int jn = (j + 1 < nbat) ? j + 1 : j;   // clamped prefetch (redundant, exact)
                LOAD_BUF8(nqB, xB, onB, jn);
                __builtin_amdgcn_sched_barrier(0);
                COMP_BUF8(xA, onA);
                j++;
                if (j >= nbat) break;
                jn = (j + 1 < nbat) ? j + 1 : j;
                LOAD_BUF8(nqA, xA, onA, jn);
                __builtin_amdgcn_sched_barrier(0);
                COMP_BUF8(xB, onB);
                j++;
            }
        }
        // ---- argmax: wave shuffle (strict >, smaller index on ties) ----
        double v = sel ? -1.0 : gg * cl;
        int idx = c0;
        for (int off = 32; off; off >>= 1) {
            double ov = __shfl_xor(v, off);
            int oi = __shfl_xor(idx, off);
            if (ov > v || (ov == v && oi < idx)) { v = ov; idx = oi; }
        }
        if (lane == 0) { rv[w] = v; ri[w] = idx; }
        __syncthreads();                           // A
        double bv = rv[0]; int mstar = ri[0];
#pragma unroll
        for (int q = 1; q < 9; q++) {
            double qv = rv[q]; int qi = ri[q];
            if (qv > bv || (qv == bv && qi < mstar)) { bv = qv; mstar = qi; }
        }
        // ---- tail: coalesced row load, cmax update, ballot ----
        float s0 = S[(size_t)mstar * NN + t];
        float o0 = mycmax, n0 = fmaxf(o0, s0);
        bool h0 = n0 > o0;
        unsigned long long m0 = __ballot(h0);
        ovnw[c0] = make_float2(o0, n0); mycmax = n0;
        if (lane == 0) chmask[w] = m0;
        if (c0 == mstar) { sel = true; selseq[k] = (float)(mstar + 1); }
        __syncthreads();                           // B
    }

    // ---- epilogue: write selection order + sorted gather list ----
    if (t < KK) out_idx[b * KK + t] = selseq[t];
    unsigned long long mk = __ballot(sel);
    if (lane == 0) wcnt[w] = __popcll(mk);
    __syncthreads();
    int r = __popcll(mk & ((1ull << lane) - 1));
    int pre = 0;
#pragma unroll
    for (int q = 0; q < 9; q++) if (q < w) pre += wcnt[q];
    if (sel) gsorted[b * KK + pre + r] = c0 + 1;
}

// ---------------- gather: dominant_tokens[b,j,:] = hs[b, gsorted, :] --------
__global__ __launch_bounds__(256) void gather_kernel(const float* __restrict__ hs,
                                                     const int* __restrict__ gsorted,
                                                     float* __restrict__ out) {
    int blk = blockIdx.x;
    int b = blk >> 7, j = blk & 127;
    int row = gsorted[b * KK + j];
    const float4* src = (const float4*)(hs + ((size_t)b * HS_N + row) * DD);
    float4* dst = (float4*)(out + ((size_t)b * KK + j) * DD);
    dst[threadIdx.x] = src[threadIdx.x];
}

extern "C" void kernel_launch(void* const* d_in, const int* in_sizes, int n_in,
                              void* d_out, int out_size, void* d_ws, size_t ws_size,
                              hipStream_t stream) {
    const float* hs = (const float*)d_in[0];
    const float* cls = (const float*)d_in[1];
    // workspace layout: sim (42.5MB) | pad (576 floats, zeroed -- dummy-column
    // landing zone for b=31) | X: inv (norm->sim) / g0 (init->select, lifetimes
    // disjoint, g0 overlays inv) | gsorted (16KB)
    float* sim = (float*)d_ws;
    float* pad = sim + (size_t)BB * NN * NN;
    char* xregion = (char*)(pad + NN);
    float* inv = (float*)xregion;                  // BB*NN floats
    double* g0 = (double*)xregion;                 // BB*NN doubles (overlay)
    int* gsorted = (int*)(xregion + (size_t)BB * NN * sizeof(double));
    float* out_tokens = (float*)d_out;                       // [B,K,D] fp32
    float* out_idx = out_tokens + (size_t)BB * KK * DD;      // [B,K] indices as fp32

    norm_kernel<<<BB * NN, 256, 0, stream>>>(hs, inv);
    sim_kernel<<<dim3(45, 1, BB), 256, 0, stream>>>(hs, inv, sim);
    init_gain_kernel<<<dim3(NN / 4, BB), 256, 0, stream>>>(sim, g0, pad);
    select_kernel<<<BB, 576, 0, stream>>>(sim, g0, cls, out_idx, gsorted);
    gather_kernel<<<BB * KK, 256, 0, stream>>>(hs, gsorted, out_tokens);
}

// Round 6
// 724.523 us; speedup vs baseline: 1.0659x; 1.0659x over previous
//
#include <hip/hip_runtime.h>

#define BB 32
#define NN 576
#define DD 1024
#define KK 128
#define HS_N 577

// ---------------- norm kernel: inv[b,n] = 1/||feats[b,n,:]|| ----------------
__global__ __launch_bounds__(256) void norm_kernel(const float* __restrict__ hs,
                                                   float* __restrict__ inv) {
    int row = blockIdx.x;              // b*NN + n
    int b = row / NN, n = row % NN;
    const float4* p = (const float4*)(hs + ((size_t)b * HS_N + n + 1) * DD);
    int t = threadIdx.x;
    float4 v = p[t];
    double s = (double)v.x * v.x + (double)v.y * v.y + (double)v.z * v.z + (double)v.w * v.w;
    for (int off = 32; off; off >>= 1) s += __shfl_xor(s, off);
    __shared__ double wsum[4];
    int lane = t & 63, w = t >> 6;
    if (lane == 0) wsum[w] = s;
    __syncthreads();
    if (t == 0) {
        double tot = wsum[0] + wsum[1] + wsum[2] + wsum[3];
        inv[row] = 1.0f / (float)sqrt(tot);
    }
}

// ---------------- sim GEMM (symmetric): only 45 upper-tri 64x64 tile pairs --
#define KC 16
#define LDT 68   // padded LDS stride
#define TLD 68   // transpose-bounce stride
__global__ __launch_bounds__(256) void sim_kernel(const float* __restrict__ hs,
                                                  const float* __restrict__ inv,
                                                  float* __restrict__ sim) {
    int b = blockIdx.z;
    int l = blockIdx.x;                // 0..44 -> (ti,tj), ti<=tj
    int ti = 0;
    while (l >= 9 - ti) { l -= 9 - ti; ti++; }
    int tj = ti + l;
    int m0 = ti * 64, n0 = tj * 64;
    const float* feats = hs + ((size_t)b * HS_N + 1) * DD;
    __shared__ float As[KC * LDT];
    __shared__ float Bs[KC * LDT];
    __shared__ float tile[64 * TLD];
    int t = threadIdx.x;
    int lrow = t >> 2, lc4 = (t & 3) << 2;     // 64 rows x 4 float4-cols
    float invA = inv[b * NN + m0 + lrow];
    float invB = inv[b * NN + n0 + lrow];
    const float* gA = feats + (size_t)(m0 + lrow) * DD + lc4;
    const float* gB = feats + (size_t)(n0 + lrow) * DD + lc4;
    int tx = t & 15, ty = t >> 4;
    float acc[4][4] = {};
    for (int k0 = 0; k0 < DD; k0 += KC) {
        float4 a = *(const float4*)(gA + k0);
        float4 bv = *(const float4*)(gB + k0);
        __syncthreads();
        // store transposed [k][m], scaled at load (matches reference normalize-then-dot)
        As[(lc4 + 0) * LDT + lrow] = a.x * invA;
        As[(lc4 + 1) * LDT + lrow] = a.y * invA;
        As[(lc4 + 2) * LDT + lrow] = a.z * invA;
        As[(lc4 + 3) * LDT + lrow] = a.w * invA;
        Bs[(lc4 + 0) * LDT + lrow] = bv.x * invB;
        Bs[(lc4 + 1) * LDT + lrow] = bv.y * invB;
        Bs[(lc4 + 2) * LDT + lrow] = bv.z * invB;
        Bs[(lc4 + 3) * LDT + lrow] = bv.w * invB;
        __syncthreads();
#pragma unroll
        for (int kk = 0; kk < KC; kk++) {
            float4 av = *(const float4*)&As[kk * LDT + (tx << 2)];
            float4 bw = *(const float4*)&Bs[kk * LDT + (ty << 2)];
            float aa[4] = {av.x, av.y, av.z, av.w};
            float bb[4] = {bw.x, bw.y, bw.z, bw.w};
#pragma unroll
            for (int i = 0; i < 4; i++)
#pragma unroll
                for (int j = 0; j < 4; j++) acc[i][j] += aa[i] * bb[j];
        }
    }
    // normal-orientation tile write (coalesced float4)
#pragma unroll
    for (int i = 0; i < 4; i++) {
        size_t m = m0 + (tx << 2) + i;
        float4 o = {acc[i][0], acc[i][1], acc[i][2], acc[i][3]};
        *(float4*)(sim + ((size_t)b * NN + m) * NN + n0 + (ty << 2)) = o;
    }
    if (ti != tj) {
        // mirror tile via LDS bounce; same float values -> bitwise symmetric
        __syncthreads();
#pragma unroll
        for (int i = 0; i < 4; i++) {
            float4 o = {acc[i][0], acc[i][1], acc[i][2], acc[i][3]};
            *(float4*)&tile[((tx << 2) + i) * TLD + (ty << 2)] = o;
        }
        __syncthreads();
#pragma unroll
        for (int r = 0; r < 4; r++) {
            int a = (tx << 2) + r;                 // local n index (output row)
            float4 o;
            o.x = tile[((ty << 2) + 0) * TLD + a];
            o.y = tile[((ty << 2) + 1) * TLD + a];
            o.z = tile[((ty << 2) + 2) * TLD + a];
            o.w = tile[((ty << 2) + 3) * TLD + a];
            *(float4*)(sim + ((size_t)b * NN + n0 + a) * NN + m0 + (ty << 2)) = o;
        }
    }
}

// -------- init gains on all CUs: g0[b,m] = sum_n max(sim[b,m,n],0) ----------
// Also zeroes the 576-float pad row after sim (dummy-column reads for b=31
// land there; b<31 dummy reads hit batch b+1's sim -- finite either way, and
// d == 0 exactly for the dummy column since its (o,nw) pair is (0,0)).
__global__ __launch_bounds__(256) void init_gain_kernel(const float* __restrict__ sim,
                                                        double* __restrict__ g0,
                                                        float* __restrict__ pad) {
    if (blockIdx.x == 0 && blockIdx.y == 0) {
        int tt = threadIdx.x;
        pad[tt] = 0.f; pad[tt + 256] = 0.f;
        if (tt < 64) pad[tt + 512] = 0.f;
    }
    int b = blockIdx.y;
    int m = (blockIdx.x << 2) + (threadIdx.x >> 6);
    int lane = threadIdx.x & 63;
    const float* row = sim + ((size_t)b * NN + m) * NN;
    double s = 0.0;
#pragma unroll
    for (int j = 0; j < 9; j++) s += (double)fmaxf(row[(j << 6) + lane], 0.f);
    for (int off = 32; off; off >>= 1) s += __shfl_xor(s, off);
    if (lane == 0) g0[b * NN + m] = s;
}

// ------- selection: 9 waves x 1 candidate, issue-lean phase 1 ---------------
// v6: round-5 showed both 1-wave-pipelined and 9-wave-TLP converge at ~475 us
// because phase 1 is ~75% ISSUE-bound (~12 instr/column/wave: chlist b32 +
// mul576 + 64b addr + load + ovnw b64 + max+min+sub+cvt+f64add). This round
// cuts instruction count, not latency:
//   (a) chlist holds BYTE OFFSETS (col*2304): load = char*-base + 32-bit
//       (choff + t*4) -> v_add_u32 + global_load off SGPR base; mul + 64-bit
//       adds gone.
//   (b) chonw side-array prefilled at scatter time with (o,nw) in chlist
//       order -> phase 1 reads float4 = 2 columns per ds_read_b128, indexed
//       by j (independent of the choff chain).
//   (c) choff batch-read as int4 (2 x ds_read_b128 per 8 columns).
//   (d) fmed3f builtin: 1 VOP3 for the validated med3 identity
//       max(x-nw,0)-max(x-o,0) == o - med3(x,o,nw)   (o <= nw, no NaNs)
// ~7 instr/column/wave. Accumulation order (j,q ascending) and all math
// bitwise-identical to v5 (absmax 0.0). Dummy pad column: choff = NN*2304
// (zeroed pad row), chonw = (0,0) -> d == 0 exactly. 9 waves (2-3/SIMD TLP,
// validated) + ILP-8 double-buffered pipeline (buffers ~48 live regs).
#define LOAD_BUF8(X, N4, J)                                                    \
    {                                                                          \
        int jj8 = (J) << 3;                                                    \
        int4 oa = *(const int4*)&choff[jj8];                                   \
        int4 ob = *(const int4*)&choff[jj8 + 4];                               \
        X[0] = *(const float*)(Sc + (unsigned)(oa.x + t4));                    \
        X[1] = *(const float*)(Sc + (unsigned)(oa.y + t4));                    \
        X[2] = *(const float*)(Sc + (unsigned)(oa.z + t4));                    \
        X[3] = *(const float*)(Sc + (unsigned)(oa.w + t4));                    \
        X[4] = *(const float*)(Sc + (unsigned)(ob.x + t4));                    \
        X[5] = *(const float*)(Sc + (unsigned)(ob.y + t4));                    \
        X[6] = *(const float*)(Sc + (unsigned)(ob.z + t4));                    \
        X[7] = *(const float*)(Sc + (unsigned)(ob.w + t4));                    \
        int jh = (J) << 2;                                                     \
        N4[0] = chonw4[jh + 0];                                                \
        N4[1] = chonw4[jh + 1];                                                \
        N4[2] = chonw4[jh + 2];                                                \
        N4[3] = chonw4[jh + 3];                                                \
    }

#define COMP_BUF8(X, N4)                                                       \
    {                                                                          \
        _Pragma("unroll") for (int q = 0; q < 4; q++) {                        \
            float o0 = N4[q].x, w0 = N4[q].y;                                  \
            gg += (double)(o0 - __builtin_amdgcn_fmed3f(X[2 * q], o0, w0));    \
            float o1 = N4[q].z, w1 = N4[q].w;                                  \
            gg += (double)(o1 - __builtin_amdgcn_fmed3f(X[2 * q + 1], o1, w1));\
        }                                                                      \
    }

__global__ __launch_bounds__(576, 1) void select_kernel(const float* __restrict__ sim,
                                                        const double* __restrict__ g0,
                                                        const float* __restrict__ cls,
                                                        float* __restrict__ out_idx,
                                                        int* __restrict__ gsorted) {
    int b = blockIdx.x;
    const float* S = sim + (size_t)b * NN * NN;
    const char* Sc = (const char*)S;
    int t = threadIdx.x, lane = t & 63, w = t >> 6;   // w in 0..8
    const int t4 = t << 2;
    __shared__ float2 ovnw[NN];            // (old cmax, new cmax) per column
    __shared__ int    choff[NN + 8];       // byte offsets col*2304, chlist order
    __shared__ float4 chonw4[(NN + 8) / 2];// (o,nw) pairs, chlist order
    __shared__ unsigned long long chmask[9];
    __shared__ double rv[9];
    __shared__ int    ri[9];
    __shared__ float  selseq[KK];
    __shared__ int    wcnt[9];
    float2* chonw = (float2*)chonw4;

    double gg = g0[b * NN + t];
    double cl = (double)cls[b * NN + t];
    float mycmax = 0.f;
    bool sel = false;
    const int c0 = t;

    for (int k = 0; k < KK; k++) {
        // ---- phase 1: delta-update over step-(k-1) changed columns ----
        if (k > 0) {
            int pos = 0;
#pragma unroll
            for (int q = 0; q < 9; q++) {
                unsigned long long m = chmask[q];
                if ((m >> lane) & 1ull) {
                    int col = (q << 6) + lane;
                    int p = pos + __popcll(m & ((1ull << lane) - 1ull));
                    choff[p] = col * 2304;
                    chonw[p] = ovnw[col];
                }
                pos += __popcll(m);
            }
            int cc = pos;
            int padc = (8 - (cc & 7)) & 7;
            if (lane < padc) {                         // dummy col: d == 0 exactly
                choff[cc + lane] = NN * 2304;
                chonw[cc + lane] = make_float2(0.f, 0.f);
            }
            int nbat = (cc + padc) >> 3;               // >= 1 (winner's row always changes)

            float xA[8]; float4 nA[4];
            float xB[8]; float4 nB[4];
            LOAD_BUF8(xA, nA, 0);
            for (int j = 0; j < nbat; ) {
                int jn = (j + 1 < nbat) ? j + 1 : j;   // clamped prefetch (redundant, exact)
                LOAD_BUF8(xB, nB, jn);
                __builtin_amdgcn_sched_barrier(0);
                COMP_BUF8(xA, nA);
                j++;
                if (j >= nbat) break;
                jn = (j + 1 < nbat) ? j + 1 : j;
                LOAD_BUF8(xA, nA, jn);
                __builtin_amdgcn_sched_barrier(0);
                COMP_BUF8(xB, nB);
                j++;
            }
        }
        // ---- argmax: wave shuffle (strict >, smaller index on ties) ----
        double v = sel ? -1.0 : gg * cl;
        int idx = c0;
        for (int off = 32; off; off >>= 1) {
            double ov = __shfl_xor(v, off);
            int oi = __shfl_xor(idx, off);
            if (ov > v || (ov == v && oi < idx)) { v = ov; idx = oi; }
        }
        if (lane == 0) { rv[w] = v; ri[w] = idx; }
        __syncthreads();                           // A
        double bv = rv[0]; int mstar = ri[0];
#pragma unroll
        for (int q = 1; q < 9; q++) {
            double qv = rv[q]; int qi = ri[q];
            if (qv > bv || (qv == bv && qi < mstar)) { bv = qv; mstar = qi; }
        }
        // ---- tail: coalesced row load, cmax update, ballot ----
        float s0 = S[(size_t)mstar * NN + t];
        float o0 = mycmax, n0 = fmaxf(o0, s0);
        bool h0 = n0 > o0;
        unsigned long long m0 = __ballot(h0);
        ovnw[c0] = make_float2(o0, n0); mycmax = n0;
        if (lane == 0) chmask[w] = m0;
        if (c0 == mstar) { sel = true; selseq[k] = (float)(mstar + 1); }
        __syncthreads();                           // B
    }

    // ---- epilogue: write selection order + sorted gather list ----
    if (t < KK) out_idx[b * KK + t] = selseq[t];
    unsigned long long mk = __ballot(sel);
    if (lane == 0) wcnt[w] = __popcll(mk);
    __syncthreads();
    int r = __popcll(mk & ((1ull << lane) - 1));
    int pre = 0;
#pragma unroll
    for (int q = 0; q < 9; q++) if (q < w) pre += wcnt[q];
    if (sel) gsorted[b * KK + pre + r] = c0 + 1;
}

// ---------------- gather: dominant_tokens[b,j,:] = hs[b, gsorted, :] --------
__global__ __launch_bounds__(256) void gather_kernel(const float* __restrict__ hs,
                                                     const int* __restrict__ gsorted,
                                                     float* __restrict__ out) {
    int blk = blockIdx.x;
    int b = blk >> 7, j = blk & 127;
    int row = gsorted[b * KK + j];
    const float4* src = (const float4*)(hs + ((size_t)b * HS_N + row) * DD);
    float4* dst = (float4*)(out + ((size_t)b * KK + j) * DD);
    dst[threadIdx.x] = src[threadIdx.x];
}

extern "C" void kernel_launch(void* const* d_in, const int* in_sizes, int n_in,
                              void* d_out, int out_size, void* d_ws, size_t ws_size,
                              hipStream_t stream) {
    const float* hs = (const float*)d_in[0];
    const float* cls = (const float*)d_in[1];
    // workspace layout: sim (42.5MB) | pad (576 floats, zeroed -- dummy-column
    // landing zone for b=31) | X: inv (norm->sim) / g0 (init->select, lifetimes
    // disjoint, g0 overlays inv) | gsorted (16KB)
    float* sim = (float*)d_ws;
    float* pad = sim + (size_t)BB * NN * NN;
    char* xregion = (char*)(pad + NN);
    float* inv = (float*)xregion;                  // BB*NN floats
    double* g0 = (double*)xregion;                 // BB*NN doubles (overlay)
    int* gsorted = (int*)(xregion + (size_t)BB * NN * sizeof(double));
    float* out_tokens = (float*)d_out;                       // [B,K,D] fp32
    float* out_idx = out_tokens + (size_t)BB * KK * DD;      // [B,K] indices as fp32

    norm_kernel<<<BB * NN, 256, 0, stream>>>(hs, inv);
    sim_kernel<<<dim3(45, 1, BB), 256, 0, stream>>>(hs, inv, sim);
    init_gain_kernel<<<dim3(NN / 4, BB), 256, 0, stream>>>(sim, g0, pad);
    select_kernel<<<BB, 576, 0, stream>>>(sim, g0, cls, out_idx, gsorted);
    gather_kernel<<<BB * KK, 256, 0, stream>>>(hs, gsorted, out_tokens);
}

// Round 7
// 720.662 us; speedup vs baseline: 1.0716x; 1.0054x over previous
//
#include <hip/hip_runtime.h>

#define BB 32
#define NN 576
#define DD 1024
#define KK 128
#define HS_N 577

// ---------------- norm kernel: inv[b,n] = 1/||feats[b,n,:]|| ----------------
__global__ __launch_bounds__(256) void norm_kernel(const float* __restrict__ hs,
                                                   float* __restrict__ inv) {
    int row = blockIdx.x;              // b*NN + n
    int b = row / NN, n = row % NN;
    const float4* p = (const float4*)(hs + ((size_t)b * HS_N + n + 1) * DD);
    int t = threadIdx.x;
    float4 v = p[t];
    double s = (double)v.x * v.x + (double)v.y * v.y + (double)v.z * v.z + (double)v.w * v.w;
    for (int off = 32; off; off >>= 1) s += __shfl_xor(s, off);
    __shared__ double wsum[4];
    int lane = t & 63, w = t >> 6;
    if (lane == 0) wsum[w] = s;
    __syncthreads();
    if (t == 0) {
        double tot = wsum[0] + wsum[1] + wsum[2] + wsum[3];
        inv[row] = 1.0f / (float)sqrt(tot);
    }
}

// ---------------- sim GEMM (symmetric): only 45 upper-tri 64x64 tile pairs --
// v7: KC 16->32 + double-buffered LDS, single barrier per k0 iter (write
// buf[cur] -> barrier -> prefetch k0+KC to regs -> compute buf[cur]).
// Barriers/block: 128 -> 32. Hazard argument: write(i+1) targets buf^1,
// last read by compute(i-1); every thread's compute(i-1) precedes its
// write(i) which precedes barrier(i), and write(i+1) follows barrier(i) ->
// no overlap. k traversal stays 0..1023 sequential (k0 asc, kk asc) with
// identical per-element products -> acc is BITWISE identical to v6's.
#define KC 32
#define LDT 68   // padded LDS stride
#define TLD 68   // transpose-bounce stride
__global__ __launch_bounds__(256) void sim_kernel(const float* __restrict__ hs,
                                                  const float* __restrict__ inv,
                                                  float* __restrict__ sim) {
    int b = blockIdx.z;
    int l = blockIdx.x;                // 0..44 -> (ti,tj), ti<=tj
    int ti = 0;
    while (l >= 9 - ti) { l -= 9 - ti; ti++; }
    int tj = ti + l;
    int m0 = ti * 64, n0 = tj * 64;
    const float* feats = hs + ((size_t)b * HS_N + 1) * DD;
    __shared__ float As[2][KC * LDT];
    __shared__ float Bs[2][KC * LDT];
    __shared__ float tile[64 * TLD];
    int t = threadIdx.x;
    int lrow = t >> 2, lc8 = (t & 3) << 3;     // 64 rows x 8 cols per thread
    float invA = inv[b * NN + m0 + lrow];
    float invB = inv[b * NN + n0 + lrow];
    const float* gA = feats + (size_t)(m0 + lrow) * DD + lc8;
    const float* gB = feats + (size_t)(n0 + lrow) * DD + lc8;
    int tx = t & 15, ty = t >> 4;
    float acc[4][4] = {};
    // preload tile 0
    float4 a0 = *(const float4*)(gA);
    float4 a1 = *(const float4*)(gA + 4);
    float4 b0 = *(const float4*)(gB);
    float4 b1 = *(const float4*)(gB + 4);
    int cur = 0;
    for (int k0 = 0; k0 < DD; k0 += KC) {
        float* Ac = As[cur];
        float* Bc = Bs[cur];
        // store transposed [k][m], scaled at load (matches reference normalize-then-dot)
        Ac[(lc8 + 0) * LDT + lrow] = a0.x * invA;
        Ac[(lc8 + 1) * LDT + lrow] = a0.y * invA;
        Ac[(lc8 + 2) * LDT + lrow] = a0.z * invA;
        Ac[(lc8 + 3) * LDT + lrow] = a0.w * invA;
        Ac[(lc8 + 4) * LDT + lrow] = a1.x * invA;
        Ac[(lc8 + 5) * LDT + lrow] = a1.y * invA;
        Ac[(lc8 + 6) * LDT + lrow] = a1.z * invA;
        Ac[(lc8 + 7) * LDT + lrow] = a1.w * invA;
        Bc[(lc8 + 0) * LDT + lrow] = b0.x * invB;
        Bc[(lc8 + 1) * LDT + lrow] = b0.y * invB;
        Bc[(lc8 + 2) * LDT + lrow] = b0.z * invB;
        Bc[(lc8 + 3) * LDT + lrow] = b0.w * invB;
        Bc[(lc8 + 4) * LDT + lrow] = b1.x * invB;
        Bc[(lc8 + 5) * LDT + lrow] = b1.y * invB;
        Bc[(lc8 + 6) * LDT + lrow] = b1.z * invB;
        Bc[(lc8 + 7) * LDT + lrow] = b1.w * invB;
        __syncthreads();
        if (k0 + KC < DD) {   // prefetch next tile under compute
            a0 = *(const float4*)(gA + k0 + KC);
            a1 = *(const float4*)(gA + k0 + KC + 4);
            b0 = *(const float4*)(gB + k0 + KC);
            b1 = *(const float4*)(gB + k0 + KC + 4);
        }
#pragma unroll
        for (int kk = 0; kk < KC; kk++) {
            float4 av = *(const float4*)&Ac[kk * LDT + (tx << 2)];
            float4 bw = *(const float4*)&Bc[kk * LDT + (ty << 2)];
            float aa[4] = {av.x, av.y, av.z, av.w};
            float bb[4] = {bw.x, bw.y, bw.z, bw.w};
#pragma unroll
            for (int i = 0; i < 4; i++)
#pragma unroll
                for (int j = 0; j < 4; j++) acc[i][j] += aa[i] * bb[j];
        }
        cur ^= 1;
    }
    // normal-orientation tile write (coalesced float4)
#pragma unroll
    for (int i = 0; i < 4; i++) {
        size_t m = m0 + (tx << 2) + i;
        float4 o = {acc[i][0], acc[i][1], acc[i][2], acc[i][3]};
        *(float4*)(sim + ((size_t)b * NN + m) * NN + n0 + (ty << 2)) = o;
    }
    if (ti != tj) {
        // mirror tile via LDS bounce; same float values -> bitwise symmetric
        __syncthreads();
#pragma unroll
        for (int i = 0; i < 4; i++) {
            float4 o = {acc[i][0], acc[i][1], acc[i][2], acc[i][3]};
            *(float4*)&tile[((tx << 2) + i) * TLD + (ty << 2)] = o;
        }
        __syncthreads();
#pragma unroll
        for (int r = 0; r < 4; r++) {
            int a = (tx << 2) + r;                 // local n index (output row)
            float4 o;
            o.x = tile[((ty << 2) + 0) * TLD + a];
            o.y = tile[((ty << 2) + 1) * TLD + a];
            o.z = tile[((ty << 2) + 2) * TLD + a];
            o.w = tile[((ty << 2) + 3) * TLD + a];
            *(float4*)(sim + ((size_t)b * NN + n0 + a) * NN + m0 + (ty << 2)) = o;
        }
    }
}

// -------- init gains on all CUs: g0[b,m] = sum_n max(sim[b,m,n],0) ----------
// Also zeroes the 576-float pad row after sim (dummy-column reads for b=31
// land there; b<31 dummy reads hit batch b+1's sim -- finite either way, and
// d == 0 exactly for the dummy column since its (o,nw) pair is (0,0)).
__global__ __launch_bounds__(256) void init_gain_kernel(const float* __restrict__ sim,
                                                        double* __restrict__ g0,
                                                        float* __restrict__ pad) {
    if (blockIdx.x == 0 && blockIdx.y == 0) {
        int tt = threadIdx.x;
        pad[tt] = 0.f; pad[tt + 256] = 0.f;
        if (tt < 64) pad[tt + 512] = 0.f;
    }
    int b = blockIdx.y;
    int m = (blockIdx.x << 2) + (threadIdx.x >> 6);
    int lane = threadIdx.x & 63;
    const float* row = sim + ((size_t)b * NN + m) * NN;
    double s = 0.0;
#pragma unroll
    for (int j = 0; j < 9; j++) s += (double)fmaxf(row[(j << 6) + lane], 0.f);
    for (int off = 32; off; off >>= 1) s += __shfl_xor(s, off);
    if (lane == 0) g0[b * NN + m] = s;
}

// ------- selection: 9 waves x 1 candidate, issue-lean + triple-buffer -------
// v7: v6's issue diet held (VALUBusy 5.1->4.5) but time only -12% -> the
// per-step FIXED serial chain dominates (phase-1 ramp latency, argmax, tail
// load, barriers). This round: (a) GUARDED prefetch -- no redundant clamped
// loads, so barrier A's implicit vmcnt(0) has nothing extra to drain;
// (b) TRIPLE buffer (prefetch j+2) so each batch's load latency is covered
// by two batches of compute+issue. Math/order bitwise-identical to v6
// (absmax 0.0): byte-offset chlist, chonw side-array, fmed3f identity
//     max(x-nw,0)-max(x-o,0) == o - med3(x,o,nw)   (o <= nw, no NaNs)
// dummy pad column choff = NN*2304 (zeroed pad row), chonw = (0,0) -> d == 0.
#define LOAD_BUF8(X, N4, J)                                                    \
    {                                                                          \
        int jj8 = (J) << 3;                                                    \
        int4 oa = *(const int4*)&choff[jj8];                                   \
        int4 ob = *(const int4*)&choff[jj8 + 4];                               \
        X[0] = *(const float*)(Sc + (unsigned)(oa.x + t4));                    \
        X[1] = *(const float*)(Sc + (unsigned)(oa.y + t4));                    \
        X[2] = *(const float*)(Sc + (unsigned)(oa.z + t4));                    \
        X[3] = *(const float*)(Sc + (unsigned)(oa.w + t4));                    \
        X[4] = *(const float*)(Sc + (unsigned)(ob.x + t4));                    \
        X[5] = *(const float*)(Sc + (unsigned)(ob.y + t4));                    \
        X[6] = *(const float*)(Sc + (unsigned)(ob.z + t4));                    \
        X[7] = *(const float*)(Sc + (unsigned)(ob.w + t4));                    \
        int jh = (J) << 2;                                                     \
        N4[0] = chonw4[jh + 0];                                                \
        N4[1] = chonw4[jh + 1];                                                \
        N4[2] = chonw4[jh + 2];                                                \
        N4[3] = chonw4[jh + 3];                                                \
    }

#define COMP_BUF8(X, N4)                                                       \
    {                                                                          \
        _Pragma("unroll") for (int q = 0; q < 4; q++) {                        \
            float o0 = N4[q].x, w0 = N4[q].y;                                  \
            gg += (double)(o0 - __builtin_amdgcn_fmed3f(X[2 * q], o0, w0));    \
            float o1 = N4[q].z, w1 = N4[q].w;                                  \
            gg += (double)(o1 - __builtin_amdgcn_fmed3f(X[2 * q + 1], o1, w1));\
        }                                                                      \
    }

__global__ __launch_bounds__(576, 1) void select_kernel(const float* __restrict__ sim,
                                                        const double* __restrict__ g0,
                                                        const float* __restrict__ cls,
                                                        float* __restrict__ out_idx,
                                                        int* __restrict__ gsorted) {
    int b = blockIdx.x;
    const float* S = sim + (size_t)b * NN * NN;
    const char* Sc = (const char*)S;
    int t = threadIdx.x, lane = t & 63, w = t >> 6;   // w in 0..8
    const int t4 = t << 2;
    __shared__ float2 ovnw[NN];            // (old cmax, new cmax) per column
    __shared__ int    choff[NN + 8];       // byte offsets col*2304, chlist order
    __shared__ float4 chonw4[(NN + 8) / 2];// (o,nw) pairs, chlist order
    __shared__ unsigned long long chmask[9];
    __shared__ double rv[9];
    __shared__ int    ri[9];
    __shared__ float  selseq[KK];
    __shared__ int    wcnt[9];
    float2* chonw = (float2*)chonw4;

    double gg = g0[b * NN + t];
    double cl = (double)cls[b * NN + t];
    float mycmax = 0.f;
    bool sel = false;
    const int c0 = t;

    for (int k = 0; k < KK; k++) {
        // ---- phase 1: delta-update over step-(k-1) changed columns ----
        if (k > 0) {
            int pos = 0;
#pragma unroll
            for (int q = 0; q < 9; q++) {
                unsigned long long m = chmask[q];
                if ((m >> lane) & 1ull) {
                    int col = (q << 6) + lane;
                    int p = pos + __popcll(m & ((1ull << lane) - 1ull));
                    choff[p] = col * 2304;
                    chonw[p] = ovnw[col];
                }
                pos += __popcll(m);
            }
            int cc = pos;
            int padc = (8 - (cc & 7)) & 7;
            if (lane < padc) {                         // dummy col: d == 0 exactly
                choff[cc + lane] = NN * 2304;
                chonw[cc + lane] = make_float2(0.f, 0.f);
            }
            int nbat = (cc + padc) >> 3;               // >= 1 (winner's row always changes)

            float xA[8]; float4 nA[4];
            float xB[8]; float4 nB[4];
            float xC[8]; float4 nC[4];
            LOAD_BUF8(xA, nA, 0);
            if (nbat > 1) LOAD_BUF8(xB, nB, 1);
            for (int j = 0; j < nbat; ) {
                if (j + 2 < nbat) LOAD_BUF8(xC, nC, j + 2);
                __builtin_amdgcn_sched_barrier(0);
                COMP_BUF8(xA, nA);
                j++;
                if (j >= nbat) break;
                if (j + 2 < nbat) LOAD_BUF8(xA, nA, j + 2);
                __builtin_amdgcn_sched_barrier(0);
                COMP_BUF8(xB, nB);
                j++;
                if (j >= nbat) break;
                if (j + 2 < nbat) LOAD_BUF8(xB, nB, j + 2);
                __builtin_amdgcn_sched_barrier(0);
                COMP_BUF8(xC, nC);
                j++;
            }
        }
        // ---- argmax: wave shuffle (strict >, smaller index on ties) ----
        double v = sel ? -1.0 : gg * cl;
        int idx = c0;
        for (int off = 32; off; off >>= 1) {
            double ov = __shfl_xor(v, off);
            int oi = __shfl_xor(idx, off);
            if (ov > v || (ov == v && oi < idx)) { v = ov; idx = oi; }
        }
        if (lane == 0) { rv[w] = v; ri[w] = idx; }
        __syncthreads();                           // A
        double bv = rv[0]; int mstar = ri[0];
#pragma unroll
        for (int q = 1; q < 9; q++) {
            double qv = rv[q]; int qi = ri[q];
            if (qv > bv || (qv == bv && qi < mstar)) { bv = qv; mstar = qi; }
        }
        // ---- tail: coalesced row load, cmax update, ballot ----
        float s0 = S[(size_t)mstar * NN + t];
        float o0 = mycmax, n0 = fmaxf(o0, s0);
        bool h0 = n0 > o0;
        unsigned long long m0 = __ballot(h0);
        ovnw[c0] = make_float2(o0, n0); mycmax = n0;
        if (lane == 0) chmask[w] = m0;
        if (c0 == mstar) { sel = true; selseq[k] = (float)(mstar + 1); }
        __syncthreads();                           // B
    }

    // ---- epilogue: write selection order + sorted gather list ----
    if (t < KK) out_idx[b * KK + t] = selseq[t];
    unsigned long long mk = __ballot(sel);
    if (lane == 0) wcnt[w] = __popcll(mk);
    __syncthreads();
    int r = __popcll(mk & ((1ull << lane) - 1));
    int pre = 0;
#pragma unroll
    for (int q = 0; q < 9; q++) if (q < w) pre += wcnt[q];
    if (sel) gsorted[b * KK + pre + r] = c0 + 1;
}

// ---------------- gather: dominant_tokens[b,j,:] = hs[b, gsorted, :] --------
__global__ __launch_bounds__(256) void gather_kernel(const float* __restrict__ hs,
                                                     const int* __restrict__ gsorted,
                                                     float* __restrict__ out) {
    int blk = blockIdx.x;
    int b = blk >> 7, j = blk & 127;
    int row = gsorted[b * KK + j];
    const float4* src = (const float4*)(hs + ((size_t)b * HS_N + row) * DD);
    float4* dst = (float4*)(out + ((size_t)b * KK + j) * DD);
    dst[threadIdx.x] = src[threadIdx.x];
}

extern "C" void kernel_launch(void* const* d_in, const int* in_sizes, int n_in,
                              void* d_out, int out_size, void* d_ws, size_t ws_size,
                              hipStream_t stream) {
    const float* hs = (const float*)d_in[0];
    const float* cls = (const float*)d_in[1];
    // workspace layout: sim (42.5MB) | pad (576 floats, zeroed -- dummy-column
    // landing zone for b=31) | X: inv (norm->sim) / g0 (init->select, lifetimes
    // disjoint, g0 overlays inv) | gsorted (16KB)
    float* sim = (float*)d_ws;
    float* pad = sim + (size_t)BB * NN * NN;
    char* xregion = (char*)(pad + NN);
    float* inv = (float*)xregion;                  // BB*NN floats
    double* g0 = (double*)xregion;                 // BB*NN doubles (overlay)
    int* gsorted = (int*)(xregion + (size_t)BB * NN * sizeof(double));
    float* out_tokens = (float*)d_out;                       // [B,K,D] fp32
    float* out_idx = out_tokens + (size_t)BB * KK * DD;      // [B,K] indices as fp32

    norm_kernel<<<BB * NN, 256, 0, stream>>>(hs, inv);
    sim_kernel<<<dim3(45, 1, BB), 256, 0, stream>>>(hs, inv, sim);
    init_gain_kernel<<<dim3(NN / 4, BB), 256, 0, stream>>>(sim, g0, pad);
    select_kernel<<<BB, 576, 0, stream>>>(sim, g0, cls, out_idx, gsorted);
    gather_kernel<<<BB * KK, 256, 0, stream>>>(hs, gsorted, out_tokens);
}

// Round 8
// 698.809 us; speedup vs baseline: 1.1051x; 1.0313x over previous
//
#include <hip/hip_runtime.h>

#define BB 32
#define NN 576
#define DD 1024
#define KK 128
#define HS_N 577

typedef float v2f __attribute__((ext_vector_type(2)));

// packed FMA: ACC = (fma(A.lo,B.lo,ACC.lo), fma(A.lo,B.hi,ACC.hi))  [broadcast A.lo]
#define PKFMA_LO(ACC, A, B)                                                    \
    asm("v_pk_fma_f32 %0, %1, %2, %0 op_sel:[0,0,0] op_sel_hi:[0,1,1]"         \
        : "+v"(ACC) : "v"(A), "v"(B))
// packed FMA: ACC = (fma(A.hi,B.lo,ACC.lo), fma(A.hi,B.hi,ACC.hi))  [broadcast A.hi]
#define PKFMA_HI(ACC, A, B)                                                    \
    asm("v_pk_fma_f32 %0, %1, %2, %0 op_sel:[1,0,0] op_sel_hi:[1,1,1]"         \
        : "+v"(ACC) : "v"(A), "v"(B))

struct V2x2 { v2f lo, hi; };

// ---------------- norm kernel: inv[b,n] = 1/||feats[b,n,:]|| ----------------
__global__ __launch_bounds__(256) void norm_kernel(const float* __restrict__ hs,
                                                   float* __restrict__ inv) {
    int row = blockIdx.x;              // b*NN + n
    int b = row / NN, n = row % NN;
    const float4* p = (const float4*)(hs + ((size_t)b * HS_N + n + 1) * DD);
    int t = threadIdx.x;
    float4 v = p[t];
    double s = (double)v.x * v.x + (double)v.y * v.y + (double)v.z * v.z + (double)v.w * v.w;
    for (int off = 32; off; off >>= 1) s += __shfl_xor(s, off);
    __shared__ double wsum[4];
    int lane = t & 63, w = t >> 6;
    if (lane == 0) wsum[w] = s;
    __syncthreads();
    if (t == 0) {
        double tot = wsum[0] + wsum[1] + wsum[2] + wsum[3];
        inv[row] = 1.0f / (float)sqrt(tot);
    }
}

// ---------------- sim GEMM (symmetric): only 45 upper-tri 64x64 tile pairs --
// v8: inner product moved to v_pk_fma_f32 (2 fused FMAs/instr, op_sel
// broadcasts the A element -- no extra movs). Same fused ops, same operand
// order, same k traversal -> acc BITWISE identical to v7 (which contracted
// to v_fmac_f32 under default -ffp-contract). Issue per kk: 16 cy pk_fma vs
// 32 cy fmac; bound shifts to the 2x ds_read_b128 (24 cy).
#define KC 32
#define LDT 68   // padded LDS stride
#define TLD 68   // transpose-bounce stride
__global__ __launch_bounds__(256) void sim_kernel(const float* __restrict__ hs,
                                                  const float* __restrict__ inv,
                                                  float* __restrict__ sim) {
    int b = blockIdx.z;
    int l = blockIdx.x;                // 0..44 -> (ti,tj), ti<=tj
    int ti = 0;
    while (l >= 9 - ti) { l -= 9 - ti; ti++; }
    int tj = ti + l;
    int m0 = ti * 64, n0 = tj * 64;
    const float* feats = hs + ((size_t)b * HS_N + 1) * DD;
    __shared__ float As[2][KC * LDT];
    __shared__ float Bs[2][KC * LDT];
    __shared__ float tile[64 * TLD];
    int t = threadIdx.x;
    int lrow = t >> 2, lc8 = (t & 3) << 3;     // 64 rows x 8 cols per thread
    float invA = inv[b * NN + m0 + lrow];
    float invB = inv[b * NN + n0 + lrow];
    const float* gA = feats + (size_t)(m0 + lrow) * DD + lc8;
    const float* gB = feats + (size_t)(n0 + lrow) * DD + lc8;
    int tx = t & 15, ty = t >> 4;
    v2f acc2[4][2] = {};                       // acc2[i][jp] = (acc[i][2jp], acc[i][2jp+1])
    // preload tile 0
    float4 a0 = *(const float4*)(gA);
    float4 a1 = *(const float4*)(gA + 4);
    float4 b0 = *(const float4*)(gB);
    float4 b1 = *(const float4*)(gB + 4);
    int cur = 0;
    for (int k0 = 0; k0 < DD; k0 += KC) {
        float* Ac = As[cur];
        float* Bc = Bs[cur];
        // store transposed [k][m], scaled at load (matches reference normalize-then-dot)
        Ac[(lc8 + 0) * LDT + lrow] = a0.x * invA;
        Ac[(lc8 + 1) * LDT + lrow] = a0.y * invA;
        Ac[(lc8 + 2) * LDT + lrow] = a0.z * invA;
        Ac[(lc8 + 3) * LDT + lrow] = a0.w * invA;
        Ac[(lc8 + 4) * LDT + lrow] = a1.x * invA;
        Ac[(lc8 + 5) * LDT + lrow] = a1.y * invA;
        Ac[(lc8 + 6) * LDT + lrow] = a1.z * invA;
        Ac[(lc8 + 7) * LDT + lrow] = a1.w * invA;
        Bc[(lc8 + 0) * LDT + lrow] = b0.x * invB;
        Bc[(lc8 + 1) * LDT + lrow] = b0.y * invB;
        Bc[(lc8 + 2) * LDT + lrow] = b0.z * invB;
        Bc[(lc8 + 3) * LDT + lrow] = b0.w * invB;
        Bc[(lc8 + 4) * LDT + lrow] = b1.x * invB;
        Bc[(lc8 + 5) * LDT + lrow] = b1.y * invB;
        Bc[(lc8 + 6) * LDT + lrow] = b1.z * invB;
        Bc[(lc8 + 7) * LDT + lrow] = b1.w * invB;
        __syncthreads();
        if (k0 + KC < DD) {   // prefetch next tile under compute
            a0 = *(const float4*)(gA + k0 + KC);
            a1 = *(const float4*)(gA + k0 + KC + 4);
            b0 = *(const float4*)(gB + k0 + KC);
            b1 = *(const float4*)(gB + k0 + KC + 4);
        }
#pragma unroll
        for (int kk = 0; kk < KC; kk++) {
            float4 av = *(const float4*)&Ac[kk * LDT + (tx << 2)];
            float4 bw = *(const float4*)&Bc[kk * LDT + (ty << 2)];
            V2x2 pa = __builtin_bit_cast(V2x2, av);   // (aa0,aa1),(aa2,aa3) -- reg pairs, no movs
            V2x2 pb = __builtin_bit_cast(V2x2, bw);   // (bb0,bb1),(bb2,bb3)
            PKFMA_LO(acc2[0][0], pa.lo, pb.lo); PKFMA_LO(acc2[0][1], pa.lo, pb.hi);
            PKFMA_HI(acc2[1][0], pa.lo, pb.lo); PKFMA_HI(acc2[1][1], pa.lo, pb.hi);
            PKFMA_LO(acc2[2][0], pa.hi, pb.lo); PKFMA_LO(acc2[2][1], pa.hi, pb.hi);
            PKFMA_HI(acc2[3][0], pa.hi, pb.lo); PKFMA_HI(acc2[3][1], pa.hi, pb.hi);
        }
        cur ^= 1;
    }
    // normal-orientation tile write (coalesced float4)
#pragma unroll
    for (int i = 0; i < 4; i++) {
        size_t m = m0 + (tx << 2) + i;
        float4 o = {acc2[i][0][0], acc2[i][0][1], acc2[i][1][0], acc2[i][1][1]};
        *(float4*)(sim + ((size_t)b * NN + m) * NN + n0 + (ty << 2)) = o;
    }
    if (ti != tj) {
        // mirror tile via LDS bounce; same float values -> bitwise symmetric
        __syncthreads();
#pragma unroll
        for (int i = 0; i < 4; i++) {
            float4 o = {acc2[i][0][0], acc2[i][0][1], acc2[i][1][0], acc2[i][1][1]};
            *(float4*)&tile[((tx << 2) + i) * TLD + (ty << 2)] = o;
        }
        __syncthreads();
#pragma unroll
        for (int r = 0; r < 4; r++) {
            int a = (tx << 2) + r;                 // local n index (output row)
            float4 o;
            o.x = tile[((ty << 2) + 0) * TLD + a];
            o.y = tile[((ty << 2) + 1) * TLD + a];
            o.z = tile[((ty << 2) + 2) * TLD + a];
            o.w = tile[((ty << 2) + 3) * TLD + a];
            *(float4*)(sim + ((size_t)b * NN + n0 + a) * NN + m0 + (ty << 2)) = o;
        }
    }
}

// -------- init gains on all CUs: g0[b,m] = sum_n max(sim[b,m,n],0) ----------
// Also zeroes the 576-float pad row after sim (dummy-column reads for b=31
// land there; b<31 dummy reads hit batch b+1's sim -- finite either way, and
// d == 0 exactly for the dummy column since its (o,nw) pair is (0,0)).
__global__ __launch_bounds__(256) void init_gain_kernel(const float* __restrict__ sim,
                                                        double* __restrict__ g0,
                                                        float* __restrict__ pad) {
    if (blockIdx.x == 0 && blockIdx.y == 0) {
        int tt = threadIdx.x;
        pad[tt] = 0.f; pad[tt + 256] = 0.f;
        if (tt < 64) pad[tt + 512] = 0.f;
    }
    int b = blockIdx.y;
    int m = (blockIdx.x << 2) + (threadIdx.x >> 6);
    int lane = threadIdx.x & 63;
    const float* row = sim + ((size_t)b * NN + m) * NN;
    double s = 0.0;
#pragma unroll
    for (int j = 0; j < 9; j++) s += (double)fmaxf(row[(j << 6) + lane], 0.f);
    for (int off = 32; off; off >>= 1) s += __shfl_xor(s, off);
    if (lane == 0) g0[b * NN + m] = s;
}

// ------- selection: 9 waves x 1 candidate, spec-tail + lean phase 1 ---------
// v8: round-7 localized the cost to the per-step SERIAL chain; the largest
// single exposed latency is the tail row load (L2-miss ~600-900 cy) sitting
// AFTER the rv/ri scan. Fix: SPECULATIVE tail -- right after barrier A, load
// S[ri[q]][t] for all 9 wave-candidates (addresses need only the fast LDS ri
// reads), overlapping the load latency with the rv scan; select the winner's
// value via an unrolled cndmask chain (static indices -> registers). Winner
// address identical to before -> identical bits. Phase 1 unchanged from v7
// (byte-offset chlist, chonw side-array, fmed3f identity, triple buffer,
// guarded prefetch; absmax 0.0 validated).
#define LOAD_BUF8(X, N4, J)                                                    \
    {                                                                          \
        int jj8 = (J) << 3;                                                    \
        int4 oa = *(const int4*)&choff[jj8];                                   \
        int4 ob = *(const int4*)&choff[jj8 + 4];                               \
        X[0] = *(const float*)(Sc + (unsigned)(oa.x + t4));                    \
        X[1] = *(const float*)(Sc + (unsigned)(oa.y + t4));                    \
        X[2] = *(const float*)(Sc + (unsigned)(oa.z + t4));                    \
        X[3] = *(const float*)(Sc + (unsigned)(oa.w + t4));                    \
        X[4] = *(const float*)(Sc + (unsigned)(ob.x + t4));                    \
        X[5] = *(const float*)(Sc + (unsigned)(ob.y + t4));                    \
        X[6] = *(const float*)(Sc + (unsigned)(ob.z + t4));                    \
        X[7] = *(const float*)(Sc + (unsigned)(ob.w + t4));                    \
        int jh = (J) << 2;                                                     \
        N4[0] = chonw4[jh + 0];                                                \
        N4[1] = chonw4[jh + 1];                                                \
        N4[2] = chonw4[jh + 2];                                                \
        N4[3] = chonw4[jh + 3];                                                \
    }

#define COMP_BUF8(X, N4)                                                       \
    {                                                                          \
        _Pragma("unroll") for (int q = 0; q < 4; q++) {                        \
            float o0 = N4[q].x, w0 = N4[q].y;                                  \
            gg += (double)(o0 - __builtin_amdgcn_fmed3f(X[2 * q], o0, w0));    \
            float o1 = N4[q].z, w1 = N4[q].w;                                  \
            gg += (double)(o1 - __builtin_amdgcn_fmed3f(X[2 * q + 1], o1, w1));\
        }                                                                      \
    }

__global__ __launch_bounds__(576, 1) void select_kernel(const float* __restrict__ sim,
                                                        const double* __restrict__ g0,
                                                        const float* __restrict__ cls,
                                                        float* __restrict__ out_idx,
                                                        int* __restrict__ gsorted) {
    int b = blockIdx.x;
    const float* S = sim + (size_t)b * NN * NN;
    const char* Sc = (const char*)S;
    int t = threadIdx.x, lane = t & 63, w = t >> 6;   // w in 0..8
    const int t4 = t << 2;
    __shared__ float2 ovnw[NN];            // (old cmax, new cmax) per column
    __shared__ int    choff[NN + 8];       // byte offsets col*2304, chlist order
    __shared__ float4 chonw4[(NN + 8) / 2];// (o,nw) pairs, chlist order
    __shared__ unsigned long long chmask[9];
    __shared__ double rv[9];
    __shared__ int    ri[9];
    __shared__ float  selseq[KK];
    __shared__ int    wcnt[9];
    float2* chonw = (float2*)chonw4;

    double gg = g0[b * NN + t];
    double cl = (double)cls[b * NN + t];
    float mycmax = 0.f;
    bool sel = false;
    const int c0 = t;

    for (int k = 0; k < KK; k++) {
        // ---- phase 1: delta-update over step-(k-1) changed columns ----
        if (k > 0) {
            int pos = 0;
#pragma unroll
            for (int q = 0; q < 9; q++) {
                unsigned long long m = chmask[q];
                if ((m >> lane) & 1ull) {
                    int col = (q << 6) + lane;
                    int p = pos + __popcll(m & ((1ull << lane) - 1ull));
                    choff[p] = col * 2304;
                    chonw[p] = ovnw[col];
                }
                pos += __popcll(m);
            }
            int cc = pos;
            int padc = (8 - (cc & 7)) & 7;
            if (lane < padc) {                         // dummy col: d == 0 exactly
                choff[cc + lane] = NN * 2304;
                chonw[cc + lane] = make_float2(0.f, 0.f);
            }
            int nbat = (cc + padc) >> 3;               // >= 1 (winner's row always changes)

            float xA[8]; float4 nA[4];
            float xB[8]; float4 nB[4];
            float xC[8]; float4 nC[4];
            LOAD_BUF8(xA, nA, 0);
            if (nbat > 1) LOAD_BUF8(xB, nB, 1);
            for (int j = 0; j < nbat; ) {
                if (j + 2 < nbat) LOAD_BUF8(xC, nC, j + 2);
                __builtin_amdgcn_sched_barrier(0);
                COMP_BUF8(xA, nA);
                j++;
                if (j >= nbat) break;
                if (j + 2 < nbat) LOAD_BUF8(xA, nA, j + 2);
                __builtin_amdgcn_sched_barrier(0);
                COMP_BUF8(xB, nB);
                j++;
                if (j >= nbat) break;
                if (j + 2 < nbat) LOAD_BUF8(xB, nB, j + 2);
                __builtin_amdgcn_sched_barrier(0);
                COMP_BUF8(xC, nC);
                j++;
            }
        }
        // ---- argmax: wave shuffle (strict >, smaller index on ties) ----
        double v = sel ? -1.0 : gg * cl;
        int idx = c0;
        for (int off = 32; off; off >>= 1) {
            double ov = __shfl_xor(v, off);
            int oi = __shfl_xor(idx, off);
            if (ov > v || (ov == v && oi < idx)) { v = ov; idx = oi; }
        }
        if (lane == 0) { rv[w] = v; ri[w] = idx; }
        __syncthreads();                           // A
        // ---- speculative tail: load all 9 candidate rows at own t, then
        //      scan rv/ri and keep the winner's value (static-index cndmask).
        int risV[9];
#pragma unroll
        for (int q = 0; q < 9; q++) risV[q] = ri[q];
        float spec[9];
#pragma unroll
        for (int q = 0; q < 9; q++) spec[q] = S[(size_t)risV[q] * NN + t];
        double bv = rv[0]; int mstar = risV[0]; float s0 = spec[0];
#pragma unroll
        for (int q = 1; q < 9; q++) {
            double qv = rv[q]; int qi = risV[q];
            bool better = qv > bv || (qv == bv && qi < mstar);
            bv = better ? qv : bv;
            mstar = better ? qi : mstar;
            s0 = better ? spec[q] : s0;
        }
        // ---- tail: cmax update, ballot (s0 == S[mstar*NN+t] bitwise) ----
        float o0 = mycmax, n0 = fmaxf(o0, s0);
        bool h0 = n0 > o0;
        unsigned long long m0 = __ballot(h0);
        ovnw[c0] = make_float2(o0, n0); mycmax = n0;
        if (lane == 0) chmask[w] = m0;
        if (c0 == mstar) { sel = true; selseq[k] = (float)(mstar + 1); }
        __syncthreads();                           // B
    }

    // ---- epilogue: write selection order + sorted gather list ----
    if (t < KK) out_idx[b * KK + t] = selseq[t];
    unsigned long long mk = __ballot(sel);
    if (lane == 0) wcnt[w] = __popcll(mk);
    __syncthreads();
    int r = __popcll(mk & ((1ull << lane) - 1));
    int pre = 0;
#pragma unroll
    for (int q = 0; q < 9; q++) if (q < w) pre += wcnt[q];
    if (sel) gsorted[b * KK + pre + r] = c0 + 1;
}

// ---------------- gather: dominant_tokens[b,j,:] = hs[b, gsorted, :] --------
__global__ __launch_bounds__(256) void gather_kernel(const float* __restrict__ hs,
                                                     const int* __restrict__ gsorted,
                                                     float* __restrict__ out) {
    int blk = blockIdx.x;
    int b = blk >> 7, j = blk & 127;
    int row = gsorted[b * KK + j];
    const float4* src = (const float4*)(hs + ((size_t)b * HS_N + row) * DD);
    float4* dst = (float4*)(out + ((size_t)b * KK + j) * DD);
    dst[threadIdx.x] = src[threadIdx.x];
}

extern "C" void kernel_launch(void* const* d_in, const int* in_sizes, int n_in,
                              void* d_out, int out_size, void* d_ws, size_t ws_size,
                              hipStream_t stream) {
    const float* hs = (const float*)d_in[0];
    const float* cls = (const float*)d_in[1];
    // workspace layout: sim (42.5MB) | pad (576 floats, zeroed -- dummy-column
    // landing zone for b=31) | X: inv (norm->sim) / g0 (init->select, lifetimes
    // disjoint, g0 overlays inv) | gsorted (16KB)
    float* sim = (float*)d_ws;
    float* pad = sim + (size_t)BB * NN * NN;
    char* xregion = (char*)(pad + NN);
    float* inv = (float*)xregion;                  // BB*NN floats
    double* g0 = (double*)xregion;                 // BB*NN doubles (overlay)
    int* gsorted = (int*)(xregion + (size_t)BB * NN * sizeof(double));
    float* out_tokens = (float*)d_out;                       // [B,K,D] fp32
    float* out_idx = out_tokens + (size_t)BB * KK * DD;      // [B,K] indices as fp32

    norm_kernel<<<BB * NN, 256, 0, stream>>>(hs, inv);
    sim_kernel<<<dim3(45, 1, BB), 256, 0, stream>>>(hs, inv, sim);
    init_gain_kernel<<<dim3(NN / 4, BB), 256, 0, stream>>>(sim, g0, pad);
    select_kernel<<<BB, 576, 0, stream>>>(sim, g0, cls, out_idx, gsorted);
    gather_kernel<<<BB * KK, 256, 0, stream>>>(hs, gsorted, out_tokens);
}

// Round 9
// 695.412 us; speedup vs baseline: 1.1105x; 1.0049x over previous
//
#include <hip/hip_runtime.h>

#define BB 32
#define NN 576
#define DD 1024
#define KK 128
#define HS_N 577

typedef float v2f __attribute__((ext_vector_type(2)));

// packed FMA: ACC = (fma(A.lo,B.lo,ACC.lo), fma(A.lo,B.hi,ACC.hi))  [broadcast A.lo]
#define PKFMA_LO(ACC, A, B)                                                    \
    asm("v_pk_fma_f32 %0, %1, %2, %0 op_sel:[0,0,0] op_sel_hi:[0,1,1]"         \
        : "+v"(ACC) : "v"(A), "v"(B))
// packed FMA: ACC = (fma(A.hi,B.lo,ACC.lo), fma(A.hi,B.hi,ACC.hi))  [broadcast A.hi]
#define PKFMA_HI(ACC, A, B)                                                    \
    asm("v_pk_fma_f32 %0, %1, %2, %0 op_sel:[1,0,0] op_sel_hi:[1,1,1]"         \
        : "+v"(ACC) : "v"(A), "v"(B))

struct V2x2 { v2f lo, hi; };

// ---------------- norm kernel: inv[b,n] = 1/||feats[b,n,:]|| ----------------
__global__ __launch_bounds__(256) void norm_kernel(const float* __restrict__ hs,
                                                   float* __restrict__ inv) {
    int row = blockIdx.x;              // b*NN + n
    int b = row / NN, n = row % NN;
    const float4* p = (const float4*)(hs + ((size_t)b * HS_N + n + 1) * DD);
    int t = threadIdx.x;
    float4 v = p[t];
    double s = (double)v.x * v.x + (double)v.y * v.y + (double)v.z * v.z + (double)v.w * v.w;
    for (int off = 32; off; off >>= 1) s += __shfl_xor(s, off);
    __shared__ double wsum[4];
    int lane = t & 63, w = t >> 6;
    if (lane == 0) wsum[w] = s;
    __syncthreads();
    if (t == 0) {
        double tot = wsum[0] + wsum[1] + wsum[2] + wsum[3];
        inv[row] = 1.0f / (float)sqrt(tot);
    }
}

// ---------------- sim GEMM (symmetric): only 45 upper-tri 64x64 tile pairs --
// v9: sim is PANEL-TRAFFIC bound (1440 blocks x 512KB panels = 737 MB; each
// batch's 2.25MB panel re-read by 9 tiles, round-robin dispatch spreads them
// over all 8 XCDs -> L2 misses). Fixes, both bitwise-identical math:
//  (a) XCD-aware swizzle: 1-D grid of 1440; id = (xcd, slot) with xcd=id&7;
//      batch b = xcd + 8*(slot/45), tile l = slot%45 -> each XCD exclusively
//      owns 4 batches; panel re-reads hit its private 4MB L2. (Bijective;
//      if HW dispatch isn't id%8 round-robin this is merely perf-neutral.)
//  (b) LDS overlay: mirror-bounce tile aliases As/Bs (dead after k-loop,
//      barrier-protected) -> 52.2KB -> 34.8KB -> 3 -> 4 blocks/CU.
// pk_fma inner loop unchanged from v8 (bitwise identical, validated).
#define KC 32
#define LDT 68   // padded LDS stride
#define TLD 68   // transpose-bounce stride
__global__ __launch_bounds__(256) void sim_kernel(const float* __restrict__ hs,
                                                  const float* __restrict__ inv,
                                                  float* __restrict__ sim) {
    int id = blockIdx.x;               // 0..1439
    int xcd = id & 7;
    int s = id >> 3;                   // 0..179
    int b = xcd + 8 * (s / 45);
    int l = s % 45;                    // 0..44 -> (ti,tj), ti<=tj
    int ti = 0;
    while (l >= 9 - ti) { l -= 9 - ti; ti++; }
    int tj = ti + l;
    int m0 = ti * 64, n0 = tj * 64;
    const float* feats = hs + ((size_t)b * HS_N + 1) * DD;
    __shared__ float smem[4][KC * LDT];        // [0..1]=A dbuf, [2..3]=B dbuf
    float* tile = (float*)smem;                // overlay: used only after k-loop
    int t = threadIdx.x;
    int lrow = t >> 2, lc8 = (t & 3) << 3;     // 64 rows x 8 cols per thread
    float invA = inv[b * NN + m0 + lrow];
    float invB = inv[b * NN + n0 + lrow];
    const float* gA = feats + (size_t)(m0 + lrow) * DD + lc8;
    const float* gB = feats + (size_t)(n0 + lrow) * DD + lc8;
    int tx = t & 15, ty = t >> 4;
    v2f acc2[4][2] = {};                       // acc2[i][jp] = (acc[i][2jp], acc[i][2jp+1])
    // preload tile 0
    float4 a0 = *(const float4*)(gA);
    float4 a1 = *(const float4*)(gA + 4);
    float4 b0 = *(const float4*)(gB);
    float4 b1 = *(const float4*)(gB + 4);
    int cur = 0;
    for (int k0 = 0; k0 < DD; k0 += KC) {
        float* Ac = smem[cur];
        float* Bc = smem[2 + cur];
        // store transposed [k][m], scaled at load (matches reference normalize-then-dot)
        Ac[(lc8 + 0) * LDT + lrow] = a0.x * invA;
        Ac[(lc8 + 1) * LDT + lrow] = a0.y * invA;
        Ac[(lc8 + 2) * LDT + lrow] = a0.z * invA;
        Ac[(lc8 + 3) * LDT + lrow] = a0.w * invA;
        Ac[(lc8 + 4) * LDT + lrow] = a1.x * invA;
        Ac[(lc8 + 5) * LDT + lrow] = a1.y * invA;
        Ac[(lc8 + 6) * LDT + lrow] = a1.z * invA;
        Ac[(lc8 + 7) * LDT + lrow] = a1.w * invA;
        Bc[(lc8 + 0) * LDT + lrow] = b0.x * invB;
        Bc[(lc8 + 1) * LDT + lrow] = b0.y * invB;
        Bc[(lc8 + 2) * LDT + lrow] = b0.z * invB;
        Bc[(lc8 + 3) * LDT + lrow] = b0.w * invB;
        Bc[(lc8 + 4) * LDT + lrow] = b1.x * invB;
        Bc[(lc8 + 5) * LDT + lrow] = b1.y * invB;
        Bc[(lc8 + 6) * LDT + lrow] = b1.z * invB;
        Bc[(lc8 + 7) * LDT + lrow] = b1.w * invB;
        __syncthreads();
        if (k0 + KC < DD) {   // prefetch next tile under compute
            a0 = *(const float4*)(gA + k0 + KC);
            a1 = *(const float4*)(gA + k0 + KC + 4);
            b0 = *(const float4*)(gB + k0 + KC);
            b1 = *(const float4*)(gB + k0 + KC + 4);
        }
#pragma unroll
        for (int kk = 0; kk < KC; kk++) {
            float4 av = *(const float4*)&Ac[kk * LDT + (tx << 2)];
            float4 bw = *(const float4*)&Bc[kk * LDT + (ty << 2)];
            V2x2 pa = __builtin_bit_cast(V2x2, av);   // (aa0,aa1),(aa2,aa3)
            V2x2 pb = __builtin_bit_cast(V2x2, bw);   // (bb0,bb1),(bb2,bb3)
            PKFMA_LO(acc2[0][0], pa.lo, pb.lo); PKFMA_LO(acc2[0][1], pa.lo, pb.hi);
            PKFMA_HI(acc2[1][0], pa.lo, pb.lo); PKFMA_HI(acc2[1][1], pa.lo, pb.hi);
            PKFMA_LO(acc2[2][0], pa.hi, pb.lo); PKFMA_LO(acc2[2][1], pa.hi, pb.hi);
            PKFMA_HI(acc2[3][0], pa.hi, pb.lo); PKFMA_HI(acc2[3][1], pa.hi, pb.hi);
        }
        cur ^= 1;
    }
    // normal-orientation tile write (coalesced float4)
#pragma unroll
    for (int i = 0; i < 4; i++) {
        size_t m = m0 + (tx << 2) + i;
        float4 o = {acc2[i][0][0], acc2[i][0][1], acc2[i][1][0], acc2[i][1][1]};
        *(float4*)(sim + ((size_t)b * NN + m) * NN + n0 + (ty << 2)) = o;
    }
    if (ti != tj) {
        // mirror tile via LDS bounce (overlaid on As/Bs -- dead after k-loop;
        // the barrier below orders last As/Bs reads before tile writes);
        // same float values -> bitwise symmetric
        __syncthreads();
#pragma unroll
        for (int i = 0; i < 4; i++) {
            float4 o = {acc2[i][0][0], acc2[i][0][1], acc2[i][1][0], acc2[i][1][1]};
            *(float4*)&tile[((tx << 2) + i) * TLD + (ty << 2)] = o;
        }
        __syncthreads();
#pragma unroll
        for (int r = 0; r < 4; r++) {
            int a = (tx << 2) + r;                 // local n index (output row)
            float4 o;
            o.x = tile[((ty << 2) + 0) * TLD + a];
            o.y = tile[((ty << 2) + 1) * TLD + a];
            o.z = tile[((ty << 2) + 2) * TLD + a];
            o.w = tile[((ty << 2) + 3) * TLD + a];
            *(float4*)(sim + ((size_t)b * NN + n0 + a) * NN + m0 + (ty << 2)) = o;
        }
    }
}

// -------- init gains on all CUs: g0[b,m] = sum_n max(sim[b,m,n],0) ----------
// Also zeroes the 576-float pad row after sim (dummy-column reads for b=31
// land there; b<31 dummy reads hit batch b+1's sim -- finite either way, and
// d == 0 exactly for the dummy column since its (o,nw) pair is (0,0)).
__global__ __launch_bounds__(256) void init_gain_kernel(const float* __restrict__ sim,
                                                        double* __restrict__ g0,
                                                        float* __restrict__ pad) {
    if (blockIdx.x == 0 && blockIdx.y == 0) {
        int tt = threadIdx.x;
        pad[tt] = 0.f; pad[tt + 256] = 0.f;
        if (tt < 64) pad[tt + 512] = 0.f;
    }
    int b = blockIdx.y;
    int m = (blockIdx.x << 2) + (threadIdx.x >> 6);
    int lane = threadIdx.x & 63;
    const float* row = sim + ((size_t)b * NN + m) * NN;
    double s = 0.0;
#pragma unroll
    for (int j = 0; j < 9; j++) s += (double)fmaxf(row[(j << 6) + lane], 0.f);
    for (int off = 32; off; off >>= 1) s += __shfl_xor(s, off);
    if (lane == 0) g0[b * NN + m] = s;
}

// ------- selection: 9 waves x 1 candidate, spec-tail + lean phase 1 ---------
// v9 = v8 unchanged (validated 422 us, absmax 0.0): byte-offset chlist,
// chonw side-array, fmed3f identity, triple-buffered guarded prefetch,
// speculative 9-candidate tail.
#define LOAD_BUF8(X, N4, J)                                                    \
    {                                                                          \
        int jj8 = (J) << 3;                                                    \
        int4 oa = *(const int4*)&choff[jj8];                                   \
        int4 ob = *(const int4*)&choff[jj8 + 4];                               \
        X[0] = *(const float*)(Sc + (unsigned)(oa.x + t4));                    \
        X[1] = *(const float*)(Sc + (unsigned)(oa.y + t4));                    \
        X[2] = *(const float*)(Sc + (unsigned)(oa.z + t4));                    \
        X[3] = *(const float*)(Sc + (unsigned)(oa.w + t4));                    \
        X[4] = *(const float*)(Sc + (unsigned)(ob.x + t4));                    \
        X[5] = *(const float*)(Sc + (unsigned)(ob.y + t4));                    \
        X[6] = *(const float*)(Sc + (unsigned)(ob.z + t4));                    \
        X[7] = *(const float*)(Sc + (unsigned)(ob.w + t4));                    \
        int jh = (J) << 2;                                                     \
        N4[0] = chonw4[jh + 0];                                                \
        N4[1] = chonw4[jh + 1];                                                \
        N4[2] = chonw4[jh + 2];                                                \
        N4[3] = chonw4[jh + 3];                                                \
    }

#define COMP_BUF8(X, N4)                                                       \
    {                                                                          \
        _Pragma("unroll") for (int q = 0; q < 4; q++) {                        \
            float o0 = N4[q].x, w0 = N4[q].y;                                  \
            gg += (double)(o0 - __builtin_amdgcn_fmed3f(X[2 * q], o0, w0));    \
            float o1 = N4[q].z, w1 = N4[q].w;                                  \
            gg += (double)(o1 - __builtin_amdgcn_fmed3f(X[2 * q + 1], o1, w1));\
        }                                                                      \
    }

__global__ __launch_bounds__(576, 1) void select_kernel(const float* __restrict__ sim,
                                                        const double* __restrict__ g0,
                                                        const float* __restrict__ cls,
                                                        float* __restrict__ out_idx,
                                                        int* __restrict__ gsorted) {
    int b = blockIdx.x;
    const float* S = sim + (size_t)b * NN * NN;
    const char* Sc = (const char*)S;
    int t = threadIdx.x, lane = t & 63, w = t >> 6;   // w in 0..8
    const int t4 = t << 2;
    __shared__ float2 ovnw[NN];            // (old cmax, new cmax) per column
    __shared__ int    choff[NN + 8];       // byte offsets col*2304, chlist order
    __shared__ float4 chonw4[(NN + 8) / 2];// (o,nw) pairs, chlist order
    __shared__ unsigned long long chmask[9];
    __shared__ double rv[9];
    __shared__ int    ri[9];
    __shared__ float  selseq[KK];
    __shared__ int    wcnt[9];
    float2* chonw = (float2*)chonw4;

    double gg = g0[b * NN + t];
    double cl = (double)cls[b * NN + t];
    float mycmax = 0.f;
    bool sel = false;
    const int c0 = t;

    for (int k = 0; k < KK; k++) {
        // ---- phase 1: delta-update over step-(k-1) changed columns ----
        if (k > 0) {
            int pos = 0;
#pragma unroll
            for (int q = 0; q < 9; q++) {
                unsigned long long m = chmask[q];
                if ((m >> lane) & 1ull) {
                    int col = (q << 6) + lane;
                    int p = pos + __popcll(m & ((1ull << lane) - 1ull));
                    choff[p] = col * 2304;
                    chonw[p] = ovnw[col];
                }
                pos += __popcll(m);
            }
            int cc = pos;
            int padc = (8 - (cc & 7)) & 7;
            if (lane < padc) {                         // dummy col: d == 0 exactly
                choff[cc + lane] = NN * 2304;
                chonw[cc + lane] = make_float2(0.f, 0.f);
            }
            int nbat = (cc + padc) >> 3;               // >= 1 (winner's row always changes)

            float xA[8]; float4 nA[4];
            float xB[8]; float4 nB[4];
            float xC[8]; float4 nC[4];
            LOAD_BUF8(xA, nA, 0);
            if (nbat > 1) LOAD_BUF8(xB, nB, 1);
            for (int j = 0; j < nbat; ) {
                if (j + 2 < nbat) LOAD_BUF8(xC, nC, j + 2);
                __builtin_amdgcn_sched_barrier(0);
                COMP_BUF8(xA, nA);
                j++;
                if (j >= nbat) break;
                if (j + 2 < nbat) LOAD_BUF8(xA, nA, j + 2);
                __builtin_amdgcn_sched_barrier(0);
                COMP_BUF8(xB, nB);
                j++;
                if (j >= nbat) break;
                if (j + 2 < nbat) LOAD_BUF8(xB, nB, j + 2);
                __builtin_amdgcn_sched_barrier(0);
                COMP_BUF8(xC, nC);
                j++;
            }
        }
        // ---- argmax: wave shuffle (strict >, smaller index on ties) ----
        double v = sel ? -1.0 : gg * cl;
        int idx = c0;
        for (int off = 32; off; off >>= 1) {
            double ov = __shfl_xor(v, off);
            int oi = __shfl_xor(idx, off);
            if (ov > v || (ov == v && oi < idx)) { v = ov; idx = oi; }
        }
        if (lane == 0) { rv[w] = v; ri[w] = idx; }
        __syncthreads();                           // A
        // ---- speculative tail: load all 9 candidate rows at own t, then
        //      scan rv/ri and keep the winner's value (static-index cndmask).
        int risV[9];
#pragma unroll
        for (int q = 0; q < 9; q++) risV[q] = ri[q];
        float spec[9];
#pragma unroll
        for (int q = 0; q < 9; q++) spec[q] = S[(size_t)risV[q] * NN + t];
        double bv = rv[0]; int mstar = risV[0]; float s0 = spec[0];
#pragma unroll
        for (int q = 1; q < 9; q++) {
            double qv = rv[q]; int qi = risV[q];
            bool better = qv > bv || (qv == bv && qi < mstar);
            bv = better ? qv : bv;
            mstar = better ? qi : mstar;
            s0 = better ? spec[q] : s0;
        }
        // ---- tail: cmax update, ballot (s0 == S[mstar*NN+t] bitwise) ----
        float o0 = mycmax, n0 = fmaxf(o0, s0);
        bool h0 = n0 > o0;
        unsigned long long m0 = __ballot(h0);
        ovnw[c0] = make_float2(o0, n0); mycmax = n0;
        if (lane == 0) chmask[w] = m0;
        if (c0 == mstar) { sel = true; selseq[k] = (float)(mstar + 1); }
        __syncthreads();                           // B
    }

    // ---- epilogue: write selection order + sorted gather list ----
    if (t < KK) out_idx[b * KK + t] = selseq[t];
    unsigned long long mk = __ballot(sel);
    if (lane == 0) wcnt[w] = __popcll(mk);
    __syncthreads();
    int r = __popcll(mk & ((1ull << lane) - 1));
    int pre = 0;
#pragma unroll
    for (int q = 0; q < 9; q++) if (q < w) pre += wcnt[q];
    if (sel) gsorted[b * KK + pre + r] = c0 + 1;
}

// ---------------- gather: dominant_tokens[b,j,:] = hs[b, gsorted, :] --------
__global__ __launch_bounds__(256) void gather_kernel(const float* __restrict__ hs,
                                                     const int* __restrict__ gsorted,
                                                     float* __restrict__ out) {
    int blk = blockIdx.x;
    int b = blk >> 7, j = blk & 127;
    int row = gsorted[b * KK + j];
    const float4* src = (const float4*)(hs + ((size_t)b * HS_N + row) * DD);
    float4* dst = (float4*)(out + ((size_t)b * KK + j) * DD);
    dst[threadIdx.x] = src[threadIdx.x];
}

extern "C" void kernel_launch(void* const* d_in, const int* in_sizes, int n_in,
                              void* d_out, int out_size, void* d_ws, size_t ws_size,
                              hipStream_t stream) {
    const float* hs = (const float*)d_in[0];
    const float* cls = (const float*)d_in[1];
    // workspace layout: sim (42.5MB) | pad (576 floats, zeroed -- dummy-column
    // landing zone for b=31) | X: inv (norm->sim) / g0 (init->select, lifetimes
    // disjoint, g0 overlays inv) | gsorted (16KB)
    float* sim = (float*)d_ws;
    float* pad = sim + (size_t)BB * NN * NN;
    char* xregion = (char*)(pad + NN);
    float* inv = (float*)xregion;                  // BB*NN floats
    double* g0 = (double*)xregion;                 // BB*NN doubles (overlay)
    int* gsorted = (int*)(xregion + (size_t)BB * NN * sizeof(double));
    float* out_tokens = (float*)d_out;                       // [B,K,D] fp32
    float* out_idx = out_tokens + (size_t)BB * KK * DD;      // [B,K] indices as fp32

    norm_kernel<<<BB * NN, 256, 0, stream>>>(hs, inv);
    sim_kernel<<<45 * BB, 256, 0, stream>>>(hs, inv, sim);
    init_gain_kernel<<<dim3(NN / 4, BB), 256, 0, stream>>>(sim, g0, pad);
    select_kernel<<<BB, 576, 0, stream>>>(sim, g0, cls, out_idx, gsorted);
    gather_kernel<<<BB * KK, 256, 0, stream>>>(hs, gsorted, out_tokens);
}

// Round 10
// 626.448 us; speedup vs baseline: 1.2328x; 1.1101x over previous
//
#include <hip/hip_runtime.h>

#define BB 32
#define NN 576
#define DD 1024
#define KK 128
#define HS_N 577

typedef float v2f __attribute__((ext_vector_type(2)));

// packed FMA: ACC = (fma(A.lo,B.lo,ACC.lo), fma(A.lo,B.hi,ACC.hi))  [broadcast A.lo]
#define PKFMA_LO(ACC, A, B)                                                    \
    asm("v_pk_fma_f32 %0, %1, %2, %0 op_sel:[0,0,0] op_sel_hi:[0,1,1]"         \
        : "+v"(ACC) : "v"(A), "v"(B))
// packed FMA: ACC = (fma(A.hi,B.lo,ACC.lo), fma(A.hi,B.hi,ACC.hi))  [broadcast A.hi]
#define PKFMA_HI(ACC, A, B)                                                    \
    asm("v_pk_fma_f32 %0, %1, %2, %0 op_sel:[1,0,0] op_sel_hi:[1,1,1]"         \
        : "+v"(ACC) : "v"(A), "v"(B))

struct V2x2 { v2f lo, hi; };

// ---------------- norm kernel: inv[b,n] = 1/||feats[b,n,:]|| ----------------
__global__ __launch_bounds__(256) void norm_kernel(const float* __restrict__ hs,
                                                   float* __restrict__ inv) {
    int row = blockIdx.x;              // b*NN + n
    int b = row / NN, n = row % NN;
    const float4* p = (const float4*)(hs + ((size_t)b * HS_N + n + 1) * DD);
    int t = threadIdx.x;
    float4 v = p[t];
    double s = (double)v.x * v.x + (double)v.y * v.y + (double)v.z * v.z + (double)v.w * v.w;
    for (int off = 32; off; off >>= 1) s += __shfl_xor(s, off);
    __shared__ double wsum[4];
    int lane = t & 63, w = t >> 6;
    if (lane == 0) wsum[w] = s;
    __syncthreads();
    if (t == 0) {
        double tot = wsum[0] + wsum[1] + wsum[2] + wsum[3];
        inv[row] = 1.0f / (float)sqrt(tot);
    }
}

// ---------------- sim GEMM (symmetric): only 45 upper-tri 64x64 tile pairs --
// v10 = v9 unchanged (XCD-chunked mapping, LDS overlay, pk_fma inner loop;
// bitwise-identical math, validated absmax 0.0).
#define KC 32
#define LDT 68   // padded LDS stride
#define TLD 68   // transpose-bounce stride
__global__ __launch_bounds__(256) void sim_kernel(const float* __restrict__ hs,
                                                  const float* __restrict__ inv,
                                                  float* __restrict__ sim) {
    int id = blockIdx.x;               // 0..1439
    int xcd = id & 7;
    int s = id >> 3;                   // 0..179
    int b = xcd + 8 * (s / 45);
    int l = s % 45;                    // 0..44 -> (ti,tj), ti<=tj
    int ti = 0;
    while (l >= 9 - ti) { l -= 9 - ti; ti++; }
    int tj = ti + l;
    int m0 = ti * 64, n0 = tj * 64;
    const float* feats = hs + ((size_t)b * HS_N + 1) * DD;
    __shared__ float smem[4][KC * LDT];        // [0..1]=A dbuf, [2..3]=B dbuf
    float* tile = (float*)smem;                // overlay: used only after k-loop
    int t = threadIdx.x;
    int lrow = t >> 2, lc8 = (t & 3) << 3;     // 64 rows x 8 cols per thread
    float invA = inv[b * NN + m0 + lrow];
    float invB = inv[b * NN + n0 + lrow];
    const float* gA = feats + (size_t)(m0 + lrow) * DD + lc8;
    const float* gB = feats + (size_t)(n0 + lrow) * DD + lc8;
    int tx = t & 15, ty = t >> 4;
    v2f acc2[4][2] = {};                       // acc2[i][jp] = (acc[i][2jp], acc[i][2jp+1])
    // preload tile 0
    float4 a0 = *(const float4*)(gA);
    float4 a1 = *(const float4*)(gA + 4);
    float4 b0 = *(const float4*)(gB);
    float4 b1 = *(const float4*)(gB + 4);
    int cur = 0;
    for (int k0 = 0; k0 < DD; k0 += KC) {
        float* Ac = smem[cur];
        float* Bc = smem[2 + cur];
        // store transposed [k][m], scaled at load (matches reference normalize-then-dot)
        Ac[(lc8 + 0) * LDT + lrow] = a0.x * invA;
        Ac[(lc8 + 1) * LDT + lrow] = a0.y * invA;
        Ac[(lc8 + 2) * LDT + lrow] = a0.z * invA;
        Ac[(lc8 + 3) * LDT + lrow] = a0.w * invA;
        Ac[(lc8 + 4) * LDT + lrow] = a1.x * invA;
        Ac[(lc8 + 5) * LDT + lrow] = a1.y * invA;
        Ac[(lc8 + 6) * LDT + lrow] = a1.z * invA;
        Ac[(lc8 + 7) * LDT + lrow] = a1.w * invA;
        Bc[(lc8 + 0) * LDT + lrow] = b0.x * invB;
        Bc[(lc8 + 1) * LDT + lrow] = b0.y * invB;
        Bc[(lc8 + 2) * LDT + lrow] = b0.z * invB;
        Bc[(lc8 + 3) * LDT + lrow] = b0.w * invB;
        Bc[(lc8 + 4) * LDT + lrow] = b1.x * invB;
        Bc[(lc8 + 5) * LDT + lrow] = b1.y * invB;
        Bc[(lc8 + 6) * LDT + lrow] = b1.z * invB;
        Bc[(lc8 + 7) * LDT + lrow] = b1.w * invB;
        __syncthreads();
        if (k0 + KC < DD) {   // prefetch next tile under compute
            a0 = *(const float4*)(gA + k0 + KC);
            a1 = *(const float4*)(gA + k0 + KC + 4);
            b0 = *(const float4*)(gB + k0 + KC);
            b1 = *(const float4*)(gB + k0 + KC + 4);
        }
#pragma unroll
        for (int kk = 0; kk < KC; kk++) {
            float4 av = *(const float4*)&Ac[kk * LDT + (tx << 2)];
            float4 bw = *(const float4*)&Bc[kk * LDT + (ty << 2)];
            V2x2 pa = __builtin_bit_cast(V2x2, av);   // (aa0,aa1),(aa2,aa3)
            V2x2 pb = __builtin_bit_cast(V2x2, bw);   // (bb0,bb1),(bb2,bb3)
            PKFMA_LO(acc2[0][0], pa.lo, pb.lo); PKFMA_LO(acc2[0][1], pa.lo, pb.hi);
            PKFMA_HI(acc2[1][0], pa.lo, pb.lo); PKFMA_HI(acc2[1][1], pa.lo, pb.hi);
            PKFMA_LO(acc2[2][0], pa.hi, pb.lo); PKFMA_LO(acc2[2][1], pa.hi, pb.hi);
            PKFMA_HI(acc2[3][0], pa.hi, pb.lo); PKFMA_HI(acc2[3][1], pa.hi, pb.hi);
        }
        cur ^= 1;
    }
    // normal-orientation tile write (coalesced float4)
#pragma unroll
    for (int i = 0; i < 4; i++) {
        size_t m = m0 + (tx << 2) + i;
        float4 o = {acc2[i][0][0], acc2[i][0][1], acc2[i][1][0], acc2[i][1][1]};
        *(float4*)(sim + ((size_t)b * NN + m) * NN + n0 + (ty << 2)) = o;
    }
    if (ti != tj) {
        // mirror tile via LDS bounce (overlaid on As/Bs -- dead after k-loop;
        // barrier orders last As/Bs reads before tile writes); bitwise symmetric
        __syncthreads();
#pragma unroll
        for (int i = 0; i < 4; i++) {
            float4 o = {acc2[i][0][0], acc2[i][0][1], acc2[i][1][0], acc2[i][1][1]};
            *(float4*)&tile[((tx << 2) + i) * TLD + (ty << 2)] = o;
        }
        __syncthreads();
#pragma unroll
        for (int r = 0; r < 4; r++) {
            int a = (tx << 2) + r;                 // local n index (output row)
            float4 o;
            o.x = tile[((ty << 2) + 0) * TLD + a];
            o.y = tile[((ty << 2) + 1) * TLD + a];
            o.z = tile[((ty << 2) + 2) * TLD + a];
            o.w = tile[((ty << 2) + 3) * TLD + a];
            *(float4*)(sim + ((size_t)b * NN + n0 + a) * NN + m0 + (ty << 2)) = o;
        }
    }
}

// -------- init gains on all CUs: g0[b,m] = sum_n max(sim[b,m,n],0) ----------
__global__ __launch_bounds__(256) void init_gain_kernel(const float* __restrict__ sim,
                                                        double* __restrict__ g0,
                                                        float* __restrict__ pad) {
    if (blockIdx.x == 0 && blockIdx.y == 0) {
        int tt = threadIdx.x;
        pad[tt] = 0.f; pad[tt + 256] = 0.f;
        if (tt < 64) pad[tt + 512] = 0.f;
    }
    int b = blockIdx.y;
    int m = (blockIdx.x << 2) + (threadIdx.x >> 6);
    int lane = threadIdx.x & 63;
    const float* row = sim + ((size_t)b * NN + m) * NN;
    double s = 0.0;
#pragma unroll
    for (int j = 0; j < 9; j++) s += (double)fmaxf(row[(j << 6) + lane], 0.f);
    for (int off = 32; off; off >>= 1) s += __shfl_xor(s, off);
    if (lane == 0) g0[b * NN + m] = s;
}

// ------- selection: 9 waves x 1 candidate, idx-free argmax ------------------
// v10: round-9 accounting -- per step ~8.0k cy, of which ~2.9k is VALU issue
// (VALUBusy 36%/active-CU) and the argmax reduce is DS-heavy: shuffling
// (v f64, idx i32) = 18 ds-ops/wave/step + 6 dependent cmp+3-cndmask rounds.
// EXACT replacement: value-only butterfly fmax (v_max_f64; v >= 0 finite, no
// NaN -> all lanes converge to identical vmax bits), then idx = (w<<6) +
// ctz(ballot(v == vmax)). Lanes are ordered by candidate index, so the lowest
// matching lane IS the smallest idx among maximizers -> winner bitwise
// identical to the old strict->/smaller-idx reduce. Same idea on the 9-slot
// scan: tree-fmax (depth 4), then first matching q ascending (ri strictly
// increases with q -> smallest ri). -6 DS and ~-36 VALU per wave per step,
// reduce chain ~2x shorter. Everything else = v8/v9 (validated absmax 0.0).
#define LOAD_BUF8(X, N4, J)                                                    \
    {                                                                          \
        int jj8 = (J) << 3;                                                    \
        int4 oa = *(const int4*)&choff[jj8];                                   \
        int4 ob = *(const int4*)&choff[jj8 + 4];                               \
        X[0] = *(const float*)(Sc + (unsigned)(oa.x + t4));                    \
        X[1] = *(const float*)(Sc + (unsigned)(oa.y + t4));                    \
        X[2] = *(const float*)(Sc + (unsigned)(oa.z + t4));                    \
        X[3] = *(const float*)(Sc + (unsigned)(oa.w + t4));                    \
        X[4] = *(const float*)(Sc + (unsigned)(ob.x + t4));                    \
        X[5] = *(const float*)(Sc + (unsigned)(ob.y + t4));                    \
        X[6] = *(const float*)(Sc + (unsigned)(ob.z + t4));                    \
        X[7] = *(const float*)(Sc + (unsigned)(ob.w + t4));                    \
        int jh = (J) << 2;                                                     \
        N4[0] = chonw4[jh + 0];                                                \
        N4[1] = chonw4[jh + 1];                                                \
        N4[2] = chonw4[jh + 2];                                                \
        N4[3] = chonw4[jh + 3];                                                \
    }

#define COMP_BUF8(X, N4)                                                       \
    {                                                                          \
        _Pragma("unroll") for (int q = 0; q < 4; q++) {                        \
            float o0 = N4[q].x, w0 = N4[q].y;                                  \
            gg += (double)(o0 - __builtin_amdgcn_fmed3f(X[2 * q], o0, w0));    \
            float o1 = N4[q].z, w1 = N4[q].w;                                  \
            gg += (double)(o1 - __builtin_amdgcn_fmed3f(X[2 * q + 1], o1, w1));\
        }                                                                      \
    }

__global__ __launch_bounds__(576, 1) void select_kernel(const float* __restrict__ sim,
                                                        const double* __restrict__ g0,
                                                        const float* __restrict__ cls,
                                                        float* __restrict__ out_idx,
                                                        int* __restrict__ gsorted) {
    int b = blockIdx.x;
    const float* S = sim + (size_t)b * NN * NN;
    const char* Sc = (const char*)S;
    int t = threadIdx.x, lane = t & 63, w = t >> 6;   // w in 0..8
    const int t4 = t << 2;
    __shared__ float2 ovnw[NN];            // (old cmax, new cmax) per column
    __shared__ int    choff[NN + 8];       // byte offsets col*2304, chlist order
    __shared__ float4 chonw4[(NN + 8) / 2];// (o,nw) pairs, chlist order
    __shared__ unsigned long long chmask[9];
    __shared__ double rv[9];
    __shared__ int    ri[9];
    __shared__ float  selseq[KK];
    __shared__ int    wcnt[9];
    float2* chonw = (float2*)chonw4;

    double gg = g0[b * NN + t];
    double cl = (double)cls[b * NN + t];
    float mycmax = 0.f;
    bool sel = false;
    const int c0 = t;

    for (int k = 0; k < KK; k++) {
        // ---- phase 1: delta-update over step-(k-1) changed columns ----
        if (k > 0) {
            int pos = 0;
#pragma unroll
            for (int q = 0; q < 9; q++) {
                unsigned long long m = chmask[q];
                if ((m >> lane) & 1ull) {
                    int col = (q << 6) + lane;
                    int p = pos + __popcll(m & ((1ull << lane) - 1ull));
                    choff[p] = col * 2304;
                    chonw[p] = ovnw[col];
                }
                pos += __popcll(m);
            }
            int cc = pos;
            int padc = (8 - (cc & 7)) & 7;
            if (lane < padc) {                         // dummy col: d == 0 exactly
                choff[cc + lane] = NN * 2304;
                chonw[cc + lane] = make_float2(0.f, 0.f);
            }
            int nbat = (cc + padc) >> 3;               // >= 1 (winner's row always changes)

            float xA[8]; float4 nA[4];
            float xB[8]; float4 nB[4];
            float xC[8]; float4 nC[4];
            LOAD_BUF8(xA, nA, 0);
            if (nbat > 1) LOAD_BUF8(xB, nB, 1);
            for (int j = 0; j < nbat; ) {
                if (j + 2 < nbat) LOAD_BUF8(xC, nC, j + 2);
                __builtin_amdgcn_sched_barrier(0);
                COMP_BUF8(xA, nA);
                j++;
                if (j >= nbat) break;
                if (j + 2 < nbat) LOAD_BUF8(xA, nA, j + 2);
                __builtin_amdgcn_sched_barrier(0);
                COMP_BUF8(xB, nB);
                j++;
                if (j >= nbat) break;
                if (j + 2 < nbat) LOAD_BUF8(xB, nB, j + 2);
                __builtin_amdgcn_sched_barrier(0);
                COMP_BUF8(xC, nC);
                j++;
            }
        }
        // ---- argmax: value-only fmax butterfly + ballot index recovery ----
        double v = sel ? -1.0 : gg * cl;               // v in {-1} U [0, inf)
        double vr = v;
        for (int off = 32; off; off >>= 1)
            vr = fmax(vr, __shfl_xor(vr, off));        // all lanes -> wave max
        unsigned long long em = __ballot(v == vr);     // maximizer lanes (nonzero)
        if (lane == 0) {
            rv[w] = vr;
            ri[w] = (w << 6) + (int)__builtin_ctzll(em);   // smallest idx maximizer
        }
        __syncthreads();                           // A
        // ---- speculative tail loads overlap the 9-slot scan ----
        int risV[9];
#pragma unroll
        for (int q = 0; q < 9; q++) risV[q] = ri[q];
        float spec[9];
#pragma unroll
        for (int q = 0; q < 9; q++) spec[q] = S[(size_t)risV[q] * NN + t];
        double rvv[9];
#pragma unroll
        for (int q = 0; q < 9; q++) rvv[q] = rv[q];
        // tree-fmax over 9 (depth 4)
        double m01 = fmax(rvv[0], rvv[1]), m23 = fmax(rvv[2], rvv[3]);
        double m45 = fmax(rvv[4], rvv[5]), m67 = fmax(rvv[6], rvv[7]);
        double m03 = fmax(m01, m23), m47 = fmax(m45, m67);
        double bv = fmax(fmax(m03, m47), rvv[8]);
        // first q (ascending) with rvv[q] == bv -> smallest ri (ri asc in q)
        int mstar = risV[8]; float s0 = spec[8];
#pragma unroll
        for (int q = 8; q >= 0; q--) {
            bool hit = (rvv[q] == bv);
            mstar = hit ? risV[q] : mstar;
            s0 = hit ? spec[q] : s0;
        }
        // ---- tail: cmax update, ballot (s0 == S[mstar*NN+t] bitwise) ----
        float o0 = mycmax, n0 = fmaxf(o0, s0);
        bool h0 = n0 > o0;
        unsigned long long m0 = __ballot(h0);
        ovnw[c0] = make_float2(o0, n0); mycmax = n0;
        if (lane == 0) chmask[w] = m0;
        if (c0 == mstar) { sel = true; selseq[k] = (float)(mstar + 1); }
        __syncthreads();                           // B
    }

    // ---- epilogue: write selection order + sorted gather list ----
    if (t < KK) out_idx[b * KK + t] = selseq[t];
    unsigned long long mk = __ballot(sel);
    if (lane == 0) wcnt[w] = __popcll(mk);
    __syncthreads();
    int r = __popcll(mk & ((1ull << lane) - 1));
    int pre = 0;
#pragma unroll
    for (int q = 0; q < 9; q++) if (q < w) pre += wcnt[q];
    if (sel) gsorted[b * KK + pre + r] = c0 + 1;
}

// ---------------- gather: dominant_tokens[b,j,:] = hs[b, gsorted, :] --------
__global__ __launch_bounds__(256) void gather_kernel(const float* __restrict__ hs,
                                                     const int* __restrict__ gsorted,
                                                     float* __restrict__ out) {
    int blk = blockIdx.x;
    int b = blk >> 7, j = blk & 127;
    int row = gsorted[b * KK + j];
    const float4* src = (const float4*)(hs + ((size_t)b * HS_N + row) * DD);
    float4* dst = (float4*)(out + ((size_t)b * KK + j) * DD);
    dst[threadIdx.x] = src[threadIdx.x];
}

extern "C" void kernel_launch(void* const* d_in, const int* in_sizes, int n_in,
                              void* d_out, int out_size, void* d_ws, size_t ws_size,
                              hipStream_t stream) {
    const float* hs = (const float*)d_in[0];
    const float* cls = (const float*)d_in[1];
    // workspace layout: sim (42.5MB) | pad (576 floats, zeroed -- dummy-column
    // landing zone for b=31) | X: inv (norm->sim) / g0 (init->select, lifetimes
    // disjoint, g0 overlays inv) | gsorted (16KB)
    float* sim = (float*)d_ws;
    float* pad = sim + (size_t)BB * NN * NN;
    char* xregion = (char*)(pad + NN);
    float* inv = (float*)xregion;                  // BB*NN floats
    double* g0 = (double*)xregion;                 // BB*NN doubles (overlay)
    int* gsorted = (int*)(xregion + (size_t)BB * NN * sizeof(double));
    float* out_tokens = (float*)d_out;                       // [B,K,D] fp32
    float* out_idx = out_tokens + (size_t)BB * KK * DD;      // [B,K] indices as fp32

    norm_kernel<<<BB * NN, 256, 0, stream>>>(hs, inv);
    sim_kernel<<<45 * BB, 256, 0, stream>>>(hs, inv, sim);
    init_gain_kernel<<<dim3(NN / 4, BB), 256, 0, stream>>>(sim, g0, pad);
    select_kernel<<<BB, 576, 0, stream>>>(sim, g0, cls, out_idx, gsorted);
    gather_kernel<<<BB * KK, 256, 0, stream>>>(hs, gsorted, out_tokens);
}